// Round 5
// baseline (1181.134 us; speedup 1.0000x reference)
//
#include <hip/hip_runtime.h>
#include <cstdint>
#include <cstddef>

#define DIN 128
#define HID 256
#define MODD 500
#define OUTD 100

typedef unsigned int uint;
typedef unsigned short ushort;
typedef __attribute__((ext_vector_type(8))) __bf16 bf16x8;
typedef __attribute__((ext_vector_type(4))) float f32x4;

__device__ __forceinline__ float bf2f(ushort u) {
    return __uint_as_float(((uint)u) << 16);
}
__device__ __forceinline__ ushort f2bf(float f) {
    uint u = __float_as_uint(f);
    return (ushort)((u + 0x7FFF + ((u >> 16) & 1)) >> 16);
}
__device__ __forceinline__ uint packbf2(float lo, float hi) {
    return (uint)f2bf(lo) | ((uint)f2bf(hi) << 16);
}
__device__ __forceinline__ void async_copy16(const void* g, void* l) {
    __builtin_amdgcn_global_load_lds((const __attribute__((address_space(1))) void*)g,
                                     (__attribute__((address_space(3))) void*)l, 16, 0, 0);
}
__device__ __forceinline__ float tanh_fast(float x) {
    // x >= 0 in our use (softplus output); stable both ends anyway
    return 1.0f - 2.0f / (__expf(2.0f * x) + 1.0f);
}
// stable fast softplus: max(v,0) + log(1 + exp(-|v|)); ~6 VALU ops vs libm's ~60+
__device__ __forceinline__ float softplus_fast(float v) {
    return fmaxf(v, 0.0f) + __logf(1.0f + __expf(-fabsf(v)));
}
// accumulate 8 bf16 (one uint4) scaled by w into a[0..8)
__device__ __forceinline__ void acc8(float* a, uint4 v, float w) {
    a[0] += w * bf2f((ushort)(v.x & 0xFFFF));
    a[1] += w * bf2f((ushort)(v.x >> 16));
    a[2] += w * bf2f((ushort)(v.y & 0xFFFF));
    a[3] += w * bf2f((ushort)(v.y >> 16));
    a[4] += w * bf2f((ushort)(v.z & 0xFFFF));
    a[5] += w * bf2f((ushort)(v.z >> 16));
    a[6] += w * bf2f((ushort)(v.w & 0xFFFF));
    a[7] += w * bf2f((ushort)(v.w >> 16));
}

// ---------------- degree / CSR build ----------------

__global__ void count_deg(const int* __restrict__ dst, int* __restrict__ deg, int E) {
    int e = blockIdx.x * blockDim.x + threadIdx.x;
    if (e < E) atomicAdd(&deg[dst[e]], 1);
}

__global__ void compute_dinv(const int* __restrict__ deg, float* __restrict__ dinv, int N) {
    int i = blockIdx.x * blockDim.x + threadIdx.x;
    if (i < N) dinv[i] = rsqrtf((float)deg[i] + 2.0f);
}

// 3-phase scan: per-block scan -> scan of block sums -> add offsets
__global__ void scan_block(const int* __restrict__ deg, int* __restrict__ rp,
                           int* __restrict__ bsum, int n) {
    __shared__ int wsum[16];
    int tid = threadIdx.x;
    int lane = tid & 63;
    int w = tid >> 6;
    int i = blockIdx.x * 1024 + tid;
    int v = (i < n) ? deg[i] : 0;
    int x = v;
    #pragma unroll
    for (int off = 1; off < 64; off <<= 1) {
        int t = __shfl_up(x, off);
        if (lane >= off) x += t;
    }
    if (lane == 63) wsum[w] = x;
    __syncthreads();
    if (tid == 0) {
        int s = 0;
        #pragma unroll
        for (int k = 0; k < 16; ++k) { int t = wsum[k]; wsum[k] = s; s += t; }
        bsum[blockIdx.x] = s;
    }
    __syncthreads();
    if (i < n) rp[i] = wsum[w] + (x - v);
}

__global__ void scan_bsums(int* __restrict__ bsum, int nb) {
    if (threadIdx.x == 0 && blockIdx.x == 0) {
        int s = 0;
        for (int k = 0; k < nb; ++k) { int t = bsum[k]; bsum[k] = s; s += t; }
        bsum[nb] = s;
    }
}

__global__ void scan_add(int* __restrict__ rp, const int* __restrict__ bsum, int n, int nb) {
    int i = blockIdx.x * blockDim.x + threadIdx.x;
    if (i < n) rp[i] += bsum[i >> 10];
    else if (i == n) rp[n] = bsum[nb];
}

// ---------------- binned edge scatter ----------------
// Buckets of 512 consecutive dst nodes occupy contiguous CSR ranges
// [rp[b*512], rp[(b+1)*512]). Pass 1 partitions edges into those ranges.
// Pass 2 (bucket_scatter) additionally SORTS each bucket's edges by src-bin
// (512-node bins) before the per-node cursor scatter, so every node's edge
// list is stored in ~ascending-src order. Concurrent waves in the aggregate
// kernels then walk X in quantile-aligned windows -> much higher L2 hit rate
// on the random row gather (the current wall: 1.64GB demand, 0.8GB L2-miss).
// Packing: src (<2^20) in low 20 bits, dst offset (<512) in bits 20..28.

#define BSH 9
#define MAXB 256
#define PCH 8192

__global__ void init_bucket_cursor(const int* __restrict__ rp, int* __restrict__ bcur,
                                   int NB) {
    int b = blockIdx.x * blockDim.x + threadIdx.x;
    if (b < NB) bcur[b] = rp[b << BSH];
}

__global__ __launch_bounds__(256)
void partition_edges(const int* __restrict__ src, const int* __restrict__ dst,
                     int* __restrict__ bcur, uint* __restrict__ pairBuf,
                     int E, int NB) {
    __shared__ int hist[MAXB];
    __shared__ int gbase[MAXB];
    int tid = threadIdx.x;
    int e0 = blockIdx.x * PCH;
    int e1 = min(e0 + PCH, E);
    for (int b = tid; b < NB; b += 256) hist[b] = 0;
    __syncthreads();
    for (int e = e0 + tid; e < e1; e += 256) {
        int d = dst[e];
        atomicAdd(&hist[d >> BSH], 1);
    }
    __syncthreads();
    for (int b = tid; b < NB; b += 256) {
        int h = hist[b];
        gbase[b] = h ? atomicAdd(&bcur[b], h) : 0;
        hist[b] = 0;
    }
    __syncthreads();
    for (int e = e0 + tid; e < e1; e += 256) {
        int d = dst[e];
        int s = src[e];
        int b = d >> BSH;
        int idx = gbase[b] + atomicAdd(&hist[b], 1);
        pairBuf[idx] = (uint)s | ((uint)(d & ((1 << BSH) - 1)) << 20);
    }
}

// per-bucket: src-bin sort (via global scratch) + per-node cursor scatter
__global__ __launch_bounds__(512)
void bucket_scatter(const uint* __restrict__ pairBuf, const int* __restrict__ rp,
                    int* __restrict__ col, uint* __restrict__ scratch, int N) {
    __shared__ int lcur[1 << BSH];
    __shared__ int hist[MAXB];
    __shared__ int bincur[MAXB];
    __shared__ int wsum2[4];
    int tid = threadIdx.x;
    int lane = tid & 63;
    int w = tid >> 6;
    int b = blockIdx.x;
    int n0 = b << BSH;
    int nn = min(1 << BSH, N - n0);
    int start = rp[n0];
    int end = rp[min(n0 + (1 << BSH), N)];

    // P1: histogram by src bin (512-node bins)
    for (int i = tid; i < MAXB; i += 512) hist[i] = 0;
    __syncthreads();
    for (int e = start + tid; e < end; e += 512)
        atomicAdd(&hist[(pairBuf[e] & 0xFFFFF) >> BSH], 1);
    __syncthreads();
    // P2: exclusive scan of 256 bins (4 waves, shfl scan)
    int xv = 0, vv = 0;
    if (tid < 256) {
        vv = hist[tid];
        xv = vv;
        #pragma unroll
        for (int off = 1; off < 64; off <<= 1) {
            int t = __shfl_up(xv, off);
            if (lane >= off) xv += t;
        }
        if (lane == 63) wsum2[w] = xv;
    }
    __syncthreads();
    if (tid == 0) {
        int s = 0;
        #pragma unroll
        for (int k = 0; k < 4; ++k) { int t = wsum2[k]; wsum2[k] = s; s += t; }
    }
    __syncthreads();
    if (tid < 256) bincur[tid] = wsum2[w] + (xv - vv);
    __syncthreads();
    // P3: scatter into src-bin-sorted order in scratch[start..end)
    for (int e = start + tid; e < end; e += 512) {
        uint v = pairBuf[e];
        int bin = (v & 0xFFFFF) >> BSH;
        int p = start + atomicAdd(&bincur[bin], 1);
        scratch[p] = v;
    }
    // P4: per-node cursor scatter (reads sorted order -> col per node ~src-ascending)
    for (int i = tid; i < nn; i += 512) lcur[i] = rp[n0 + i];
    __syncthreads();
    for (int e = start + tid; e < end; e += 512) {
        uint v = scratch[e];
        int doff = v >> 20;
        int s = v & 0xFFFFF;
        int pos = atomicAdd(&lcur[doff], 1);
        col[pos] = s;
    }
}

// ---------------- casts / transposes ----------------

__global__ void cast_f32_bf16(const float* __restrict__ src, ushort* __restrict__ dst, int n4) {
    int i = blockIdx.x * blockDim.x + threadIdx.x;
    if (i < n4) {
        float4 v = ((const float4*)src)[i];
        ushort4 o;
        o.x = f2bf(v.x); o.y = f2bf(v.y); o.z = f2bf(v.z); o.w = f2bf(v.w);
        ((ushort4*)dst)[i] = o;
    }
}

// src[K][N] fp32 -> dst[Npad][Kpad] bf16 (zero padded)
__global__ void transpose_cast(const float* __restrict__ src, ushort* __restrict__ dst,
                               int K, int N, int Kpad, int Npad) {
    int idx = blockIdx.x * blockDim.x + threadIdx.x;
    if (idx >= Npad * Kpad) return;
    int n = idx / Kpad, k = idx - n * Kpad;
    float v = (n < N && k < K) ? src[(size_t)k * N + n] : 0.0f;
    dst[idx] = f2bf(v);
}

// ---------------- aggregation (gather over CSR, bf16 rows, fp32 accum) ----------------
// Y[n] = 2*dinv[n]^2 * X[n] + sum_{e in in(n)} dinv[src]*dinv[n] * X[src]
// Split-wave wide gathers (R4 form). Edge lists are ~src-sorted (bucket_scatter),
// so concurrent waves walk X in quantile-aligned windows for L2 locality.

// D = 128 bf16 (256B rows = 16 uint4): 4 groups of 16 lanes, 4 rows/load
__global__ void aggregate128(const ushort* __restrict__ X, ushort* __restrict__ Y,
                             const int* __restrict__ rp, const int* __restrict__ col,
                             const float* __restrict__ dinv, int N) {
    int gw = blockIdx.x * (blockDim.x >> 6) + (threadIdx.x >> 6);
    int lane = threadIdx.x & 63;
    if (gw >= N) return;
    int g = lane >> 4;        // edge parity class 0..3
    int sub = lane & 15;      // uint4 index within row
    float di = dinv[gw];
    float sc = 2.0f * di * di;
    const uint4* Xr = (const uint4*)X;   // row stride = 16 uint4
    float a[8] = {};
    if (g == 0) acc8(a, Xr[(size_t)gw * 16 + sub], sc);   // self term
    int e = rp[gw], end = rp[gw + 1];
    int base = e;
    for (; base + 8 <= end; base += 8) {
        int c0 = col[base + g];
        int c1 = col[base + 4 + g];
        float w0 = dinv[c0] * di, w1 = dinv[c1] * di;
        uint4 v0 = Xr[(size_t)c0 * 16 + sub];
        uint4 v1 = Xr[(size_t)c1 * 16 + sub];
        acc8(a, v0, w0);
        acc8(a, v1, w1);
    }
    if (base + 4 <= end) {
        int c0 = col[base + g];
        float w0 = dinv[c0] * di;
        acc8(a, Xr[(size_t)c0 * 16 + sub], w0);
        base += 4;
    }
    int rem = end - base;    // 0..3
    if (g < rem) {
        int c0 = col[base + g];
        float w0 = dinv[c0] * di;
        acc8(a, Xr[(size_t)c0 * 16 + sub], w0);
    }
    #pragma unroll
    for (int q = 0; q < 8; ++q) {
        a[q] += __shfl_xor(a[q], 16);
        a[q] += __shfl_xor(a[q], 32);
    }
    if (g == 0) {
        uint4 o;
        o.x = packbf2(a[0], a[1]);
        o.y = packbf2(a[2], a[3]);
        o.z = packbf2(a[4], a[5]);
        o.w = packbf2(a[6], a[7]);
        ((uint4*)Y)[(size_t)gw * 16 + sub] = o;
    }
}

// D = 256 bf16 (512B rows = 32 uint4): 2 groups of 32 lanes, 2 rows/load
__global__ void aggregate256(const ushort* __restrict__ X, ushort* __restrict__ Y,
                             const int* __restrict__ rp, const int* __restrict__ col,
                             const float* __restrict__ dinv, int N) {
    int gw = blockIdx.x * (blockDim.x >> 6) + (threadIdx.x >> 6);
    int lane = threadIdx.x & 63;
    if (gw >= N) return;
    int g = lane >> 5;        // edge parity class 0..1
    int sub = lane & 31;      // uint4 index within row
    float di = dinv[gw];
    float sc = 2.0f * di * di;
    const uint4* Xr = (const uint4*)X;   // row stride = 32 uint4
    float a[8] = {};
    if (g == 0) acc8(a, Xr[(size_t)gw * 32 + sub], sc);   // self term
    int e = rp[gw], end = rp[gw + 1];
    int base = e;
    for (; base + 4 <= end; base += 4) {
        int c0 = col[base + g];
        int c1 = col[base + 2 + g];
        float w0 = dinv[c0] * di, w1 = dinv[c1] * di;
        uint4 v0 = Xr[(size_t)c0 * 32 + sub];
        uint4 v1 = Xr[(size_t)c1 * 32 + sub];
        acc8(a, v0, w0);
        acc8(a, v1, w1);
    }
    if (base + 2 <= end) {
        int c0 = col[base + g];
        float w0 = dinv[c0] * di;
        acc8(a, Xr[(size_t)c0 * 32 + sub], w0);
        base += 2;
    }
    if (base < end && g == 0) {   // one leftover edge
        int c0 = col[base];
        float w0 = dinv[c0] * di;
        acc8(a, Xr[(size_t)c0 * 32 + sub], w0);
    }
    #pragma unroll
    for (int q = 0; q < 8; ++q) a[q] += __shfl_xor(a[q], 32);
    if (g == 0) {
        uint4 o;
        o.x = packbf2(a[0], a[1]);
        o.y = packbf2(a[2], a[3]);
        o.z = packbf2(a[4], a[5]);
        o.w = packbf2(a[6], a[7]);
        ((uint4*)Y)[(size_t)gw * 32 + sub] = o;
    }
}

// ---------------- bf16 MFMA GEMM (m97 structure) ----------------
// C[M,Nact] = epi(A[M,K]_bf16 @ BT[Npad,K]_bf16^T + bias)
// BM=128, BN=128, BK=32, 256 threads = 4 waves, each wave 64x64 (4x4 MFMA tiles)
// MODE 0: relu -> bf16 store
// MODE 2: plain -> f32 store (nontemporal; never re-read)
// MODE 3: softplus -> f32 store (Cout, nontemporal) AND tanh(sp*softplus) -> bf16
//         store (C2, ld 512, cols [Nact,512) zeroed) — feeds the head GEMM.

template<int K, int MODE>
__global__ __launch_bounds__(256)
void gemm_bt(const ushort* __restrict__ A, const ushort* __restrict__ BT,
             const float* __restrict__ bias, void* __restrict__ Cout,
             int M, int Nact, int ldc, ushort* __restrict__ C2,
             const float* __restrict__ thr) {
    __shared__ ushort sA[128 * 32];
    __shared__ ushort sB[128 * 32];
    int tid = threadIdx.x;
    int lane = tid & 63;
    int w = tid >> 6;
    int wr = w >> 1, wc = w & 1;
    int row0 = blockIdx.y * 128;
    int col0 = blockIdx.x * 128;
    float sp = 0.0f;
    if (MODE == 3) sp = softplus_fast(*thr);
    f32x4 acc[4][4] = {};

    for (int kt = 0; kt < K; kt += 32) {
        if (kt) __syncthreads();
        #pragma unroll
        for (int L = 0; L < 2; ++L) {
            int cb = L * 256 + w * 64;
            int c = cb + lane;
            int r = c >> 2;
            int ko = (c & 3) * 8;
            int rr = min(row0 + r, M - 1);
            async_copy16(A + (size_t)rr * K + kt + ko, sA + (size_t)cb * 8);
        }
        #pragma unroll
        for (int L = 0; L < 2; ++L) {
            int cb = L * 256 + w * 64;
            int c = cb + lane;
            int nr = c >> 2;
            int ko = (c & 3) * 8;
            async_copy16(BT + (size_t)(col0 + nr) * K + kt + ko, sB + (size_t)cb * 8);
        }
        __syncthreads();
        bf16x8 af[4], bfr[4];
        #pragma unroll
        for (int i = 0; i < 4; ++i) {
            int row = wr * 64 + i * 16 + (lane & 15);
            af[i] = *(const bf16x8*)(sA + row * 32 + (lane >> 4) * 8);
        }
        #pragma unroll
        for (int j = 0; j < 4; ++j) {
            int n = wc * 64 + j * 16 + (lane & 15);
            bfr[j] = *(const bf16x8*)(sB + n * 32 + (lane >> 4) * 8);
        }
        #pragma unroll
        for (int i = 0; i < 4; ++i)
            #pragma unroll
            for (int j = 0; j < 4; ++j)
                acc[i][j] = __builtin_amdgcn_mfma_f32_16x16x32_bf16(af[i], bfr[j], acc[i][j], 0, 0, 0);
    }

    #pragma unroll
    for (int i = 0; i < 4; ++i) {
        #pragma unroll
        for (int j = 0; j < 4; ++j) {
            int col = col0 + wc * 64 + j * 16 + (lane & 15);
            if (MODE == 3) {
                bool act = (col < Nact);
                float bv = act ? bias[col] : 0.0f;
                #pragma unroll
                for (int r = 0; r < 4; ++r) {
                    int row = row0 + wr * 64 + i * 16 + (lane >> 4) * 4 + r;
                    if (row >= M) continue;
                    if (act) {
                        float v = softplus_fast(acc[i][j][r] + bv);
                        __builtin_nontemporal_store(v, &((float*)Cout)[(size_t)row * ldc + col]);
                        C2[(size_t)row * 512 + col] = f2bf(tanh_fast(sp * v));
                    } else {
                        C2[(size_t)row * 512 + col] = 0;
                    }
                }
            } else {
                if (col >= Nact) continue;
                float bv = bias[col];
                #pragma unroll
                for (int r = 0; r < 4; ++r) {
                    int row = row0 + wr * 64 + i * 16 + (lane >> 4) * 4 + r;
                    if (row >= M) continue;
                    float v = acc[i][j][r] + bv;
                    if (MODE == 0) {
                        v = fmaxf(v, 0.0f);
                        ((ushort*)Cout)[(size_t)row * ldc + col] = f2bf(v);
                    } else {
                        __builtin_nontemporal_store(v, &((float*)Cout)[(size_t)row * ldc + col]);
                    }
                }
            }
        }
    }
}

// ---------------- launch ----------------

extern "C" void kernel_launch(void* const* d_in, const int* in_sizes, int n_in,
                              void* d_out, int out_size, void* d_ws, size_t ws_size,
                              hipStream_t stream) {
    const float* x    = (const float*)d_in[0];
    const int*   ei   = (const int*)d_in[1];
    const float* W1   = (const float*)d_in[2];
    const float* b1   = (const float*)d_in[3];
    const float* W2   = (const float*)d_in[4];
    const float* b2   = (const float*)d_in[5];
    const float* Wout = (const float*)d_in[6];
    const float* bout = (const float*)d_in[7];
    const float* thr  = (const float*)d_in[8];

    int N = in_sizes[0] / DIN;
    int E = in_sizes[1] / 2;
    const int* srcI = ei;
    const int* dstI = ei + E;

    char* wsp = (char*)d_ws;
    size_t o = 0;
    auto alloc = [&](size_t bytes) -> void* {
        void* p = wsp + o;
        o = (o + bytes + 255) & ~(size_t)255;
        return p;
    };
    int*    deg   = (int*)alloc((size_t)N * 4);
    float*  dinv  = (float*)alloc((size_t)N * 4);
    int*    rp    = (int*)alloc((size_t)(N + 1) * 4);
    int*    bsum  = (int*)alloc(1024);
    int*    bcur  = (int*)alloc(MAXB * 4);
    ushort* W1T   = (ushort*)alloc((size_t)256 * 128 * 2);
    ushort* W2T   = (ushort*)alloc((size_t)512 * 256 * 2);
    ushort* WoutT = (ushort*)alloc((size_t)128 * 512 * 2);
    ushort* bufA  = (ushort*)alloc((size_t)N * 256 * 2);  // scratch, then xbf+xa, later ha
    // col + hbuf live contiguously; after aggregate256 both are dead and the
    // region is reused as pbf [N,512] bf16 (tanh(sp*softplus) activations).
    size_t  col_off = o;
    int*    col   = (int*)alloc((size_t)E * 4);
    ushort* hbuf  = (ushort*)alloc((size_t)N * 256 * 2);  // h bf16 (pairBuf before gemm1)
    size_t  pbf_need = col_off + (size_t)N * 512 * 2;
    if (o < pbf_need) o = (pbf_need + 255) & ~(size_t)255;
    ushort* pbf = (ushort*)(wsp + col_off);               // [N,512] bf16

    ushort* xbf = bufA;                       // [N,128] bf16
    ushort* xa  = bufA + (size_t)N * 128;     // [N,128] bf16
    ushort* ha  = bufA;                       // [N,256] bf16 (reuses xbf+xa)
    uint* pairBuf = (uint*)hbuf;              // [E] packed edges (dead before gemm1 writes hbuf)
    uint* scratch = (uint*)bufA;              // [E] sort scratch (dead before cast writes xbf)

    float* mr   = (float*)d_out;                    // [N,500]
    float* yout = (float*)d_out + (size_t)N * MODD; // [N,100]

    int mtiles = (N + 127) / 128;
    int NB = (N + (1 << BSH) - 1) >> BSH;           // node-range buckets (196 for N=100K)

    // --- CSR build ---
    hipMemsetAsync(deg, 0, (size_t)N * 4, stream);
    count_deg<<<(E + 255) / 256, 256, 0, stream>>>(dstI, deg, E);
    compute_dinv<<<(N + 255) / 256, 256, 0, stream>>>(deg, dinv, N);
    int nb = (N + 1023) / 1024;
    scan_block<<<nb, 1024, 0, stream>>>(deg, rp, bsum, N);
    scan_bsums<<<1, 64, 0, stream>>>(bsum, nb);
    scan_add<<<(N + 256) / 256, 256, 0, stream>>>(rp, bsum, N, nb);
    // binned 2-pass edge scatter, with per-bucket src-bin sort
    init_bucket_cursor<<<1, 256, 0, stream>>>(rp, bcur, NB);
    partition_edges<<<(E + PCH - 1) / PCH, 256, 0, stream>>>(srcI, dstI, bcur, pairBuf, E, NB);
    bucket_scatter<<<NB, 512, 0, stream>>>(pairBuf, rp, col, scratch, N);

    // --- weight prep (cast AFTER bucket_scatter: xbf region doubles as sort scratch) ---
    cast_f32_bf16<<<((N * DIN / 4) + 255) / 256, 256, 0, stream>>>(x, xbf, N * DIN / 4);
    transpose_cast<<<(256 * 128 + 255) / 256, 256, 0, stream>>>(W1, W1T, 128, 256, 128, 256);
    transpose_cast<<<(512 * 256 + 255) / 256, 256, 0, stream>>>(W2, W2T, 256, 500, 256, 512);
    transpose_cast<<<(128 * 512 + 255) / 256, 256, 0, stream>>>(Wout, WoutT, 500, 100, 512, 128);

    // --- conv1 ---
    aggregate128<<<(N + 3) / 4, 256, 0, stream>>>(xbf, xa, rp, col, dinv, N);
    gemm_bt<128, 0><<<dim3(2, mtiles), 256, 0, stream>>>(xa, W1T, b1, hbuf, N, HID, HID,
                                                         nullptr, nullptr);

    // --- conv2 (epilogue also emits tanh(sp*softplus) bf16 into pbf) ---
    aggregate256<<<(N + 3) / 4, 256, 0, stream>>>(hbuf, ha, rp, col, dinv, N);
    gemm_bt<256, 3><<<dim3(4, mtiles), 256, 0, stream>>>(ha, W2T, b2, mr, N, MODD, MODD,
                                                         pbf, thr);

    // --- head: y = pbf @ Wout + bout ---
    gemm_bt<512, 2><<<dim3(1, mtiles), 256, 0, stream>>>(pbf, WoutT, bout, yout, N, OUTD, OUTD,
                                                         nullptr, nullptr);
}

// Round 6
// 1103.655 us; speedup vs baseline: 1.0702x; 1.0702x over previous
//
#include <hip/hip_runtime.h>
#include <cstdint>
#include <cstddef>

#define DIN 128
#define HID 256
#define MODD 500
#define OUTD 100

typedef unsigned int uint;
typedef unsigned short ushort;
typedef __attribute__((ext_vector_type(8))) __bf16 bf16x8;
typedef __attribute__((ext_vector_type(4))) float f32x4;

__device__ __forceinline__ float bf2f(ushort u) {
    return __uint_as_float(((uint)u) << 16);
}
__device__ __forceinline__ ushort f2bf(float f) {
    uint u = __float_as_uint(f);
    return (ushort)((u + 0x7FFF + ((u >> 16) & 1)) >> 16);
}
__device__ __forceinline__ uint packbf2(float lo, float hi) {
    return (uint)f2bf(lo) | ((uint)f2bf(hi) << 16);
}
__device__ __forceinline__ void async_copy16(const void* g, void* l) {
    __builtin_amdgcn_global_load_lds((const __attribute__((address_space(1))) void*)g,
                                     (__attribute__((address_space(3))) void*)l, 16, 0, 0);
}
__device__ __forceinline__ float tanh_fast(float x) {
    // x >= 0 in our use (softplus output); stable both ends anyway
    return 1.0f - 2.0f / (__expf(2.0f * x) + 1.0f);
}
// stable fast softplus: max(v,0) + log(1 + exp(-|v|)); ~6 VALU ops vs libm's ~60+
__device__ __forceinline__ float softplus_fast(float v) {
    return fmaxf(v, 0.0f) + __logf(1.0f + __expf(-fabsf(v)));
}
// accumulate 8 bf16 (one uint4) scaled by w into a[0..8)
__device__ __forceinline__ void acc8(float* a, uint4 v, float w) {
    a[0] += w * bf2f((ushort)(v.x & 0xFFFF));
    a[1] += w * bf2f((ushort)(v.x >> 16));
    a[2] += w * bf2f((ushort)(v.y & 0xFFFF));
    a[3] += w * bf2f((ushort)(v.y >> 16));
    a[4] += w * bf2f((ushort)(v.z & 0xFFFF));
    a[5] += w * bf2f((ushort)(v.z >> 16));
    a[6] += w * bf2f((ushort)(v.w & 0xFFFF));
    a[7] += w * bf2f((ushort)(v.w >> 16));
}

// ---------------- degree / CSR build ----------------

__global__ void count_deg(const int* __restrict__ dst, int* __restrict__ deg, int E) {
    int e = blockIdx.x * blockDim.x + threadIdx.x;
    if (e < E) atomicAdd(&deg[dst[e]], 1);
}

__global__ void compute_dinv(const int* __restrict__ deg, float* __restrict__ dinv, int N) {
    int i = blockIdx.x * blockDim.x + threadIdx.x;
    if (i < N) dinv[i] = rsqrtf((float)deg[i] + 2.0f);
}

// 3-phase scan: per-block scan -> scan of block sums -> add offsets
__global__ void scan_block(const int* __restrict__ deg, int* __restrict__ rp,
                           int* __restrict__ bsum, int n) {
    __shared__ int wsum[16];
    int tid = threadIdx.x;
    int lane = tid & 63;
    int w = tid >> 6;
    int i = blockIdx.x * 1024 + tid;
    int v = (i < n) ? deg[i] : 0;
    int x = v;
    #pragma unroll
    for (int off = 1; off < 64; off <<= 1) {
        int t = __shfl_up(x, off);
        if (lane >= off) x += t;
    }
    if (lane == 63) wsum[w] = x;
    __syncthreads();
    if (tid == 0) {
        int s = 0;
        #pragma unroll
        for (int k = 0; k < 16; ++k) { int t = wsum[k]; wsum[k] = s; s += t; }
        bsum[blockIdx.x] = s;
    }
    __syncthreads();
    if (i < n) rp[i] = wsum[w] + (x - v);
}

__global__ void scan_bsums(int* __restrict__ bsum, int nb) {
    if (threadIdx.x == 0 && blockIdx.x == 0) {
        int s = 0;
        for (int k = 0; k < nb; ++k) { int t = bsum[k]; bsum[k] = s; s += t; }
        bsum[nb] = s;
    }
}

__global__ void scan_add(int* __restrict__ rp, const int* __restrict__ bsum, int n, int nb) {
    int i = blockIdx.x * blockDim.x + threadIdx.x;
    if (i < n) rp[i] += bsum[i >> 10];
    else if (i == n) rp[n] = bsum[nb];
}

// ---------------- binned edge scatter ----------------
// Buckets of 512 consecutive dst nodes occupy contiguous CSR ranges
// [rp[b*512], rp[(b+1)*512]). Pass 1 partitions edges into those ranges.
// Pass 2 (bucket_scatter) additionally SORTS each bucket's edges by src-bin
// (512-node bins) before the per-node cursor scatter, so every node's edge
// list is stored in ~ascending-src order. Concurrent waves in the aggregate
// kernels then walk X in quantile-aligned windows -> much higher L2 hit rate
// (verified R5: aggregate256 dropped out of the top-5).
// Packing: src (<2^20) in low 20 bits, dst offset (<512) in bits 20..28.

#define BSH 9
#define MAXB 256
#define PCH 8192

__global__ void init_bucket_cursor(const int* __restrict__ rp, int* __restrict__ bcur,
                                   int NB) {
    int b = blockIdx.x * blockDim.x + threadIdx.x;
    if (b < NB) bcur[b] = rp[b << BSH];
}

__global__ __launch_bounds__(256)
void partition_edges(const int* __restrict__ src, const int* __restrict__ dst,
                     int* __restrict__ bcur, uint* __restrict__ pairBuf,
                     int E, int NB) {
    __shared__ int hist[MAXB];
    __shared__ int gbase[MAXB];
    int tid = threadIdx.x;
    int e0 = blockIdx.x * PCH;
    int e1 = min(e0 + PCH, E);
    for (int b = tid; b < NB; b += 256) hist[b] = 0;
    __syncthreads();
    for (int e = e0 + tid; e < e1; e += 256) {
        int d = dst[e];
        atomicAdd(&hist[d >> BSH], 1);
    }
    __syncthreads();
    for (int b = tid; b < NB; b += 256) {
        int h = hist[b];
        gbase[b] = h ? atomicAdd(&bcur[b], h) : 0;
        hist[b] = 0;
    }
    __syncthreads();
    for (int e = e0 + tid; e < e1; e += 256) {
        int d = dst[e];
        int s = src[e];
        int b = d >> BSH;
        int idx = gbase[b] + atomicAdd(&hist[b], 1);
        pairBuf[idx] = (uint)s | ((uint)(d & ((1 << BSH) - 1)) << 20);
    }
}

// per-bucket: src-bin sort (via global scratch) + per-node cursor scatter
__global__ __launch_bounds__(512)
void bucket_scatter(const uint* __restrict__ pairBuf, const int* __restrict__ rp,
                    int* __restrict__ col, uint* __restrict__ scratch, int N) {
    __shared__ int lcur[1 << BSH];
    __shared__ int hist[MAXB];
    __shared__ int bincur[MAXB];
    __shared__ int wsum2[4];
    int tid = threadIdx.x;
    int lane = tid & 63;
    int w = tid >> 6;
    int b = blockIdx.x;
    int n0 = b << BSH;
    int nn = min(1 << BSH, N - n0);
    int start = rp[n0];
    int end = rp[min(n0 + (1 << BSH), N)];

    // P1: histogram by src bin (512-node bins)
    for (int i = tid; i < MAXB; i += 512) hist[i] = 0;
    __syncthreads();
    for (int e = start + tid; e < end; e += 512)
        atomicAdd(&hist[(pairBuf[e] & 0xFFFFF) >> BSH], 1);
    __syncthreads();
    // P2: exclusive scan of 256 bins (4 waves, shfl scan)
    int xv = 0, vv = 0;
    if (tid < 256) {
        vv = hist[tid];
        xv = vv;
        #pragma unroll
        for (int off = 1; off < 64; off <<= 1) {
            int t = __shfl_up(xv, off);
            if (lane >= off) xv += t;
        }
        if (lane == 63) wsum2[w] = xv;
    }
    __syncthreads();
    if (tid == 0) {
        int s = 0;
        #pragma unroll
        for (int k = 0; k < 4; ++k) { int t = wsum2[k]; wsum2[k] = s; s += t; }
    }
    __syncthreads();
    if (tid < 256) bincur[tid] = wsum2[w] + (xv - vv);
    __syncthreads();
    // P3: scatter into src-bin-sorted order in scratch[start..end)
    for (int e = start + tid; e < end; e += 512) {
        uint v = pairBuf[e];
        int bin = (v & 0xFFFFF) >> BSH;
        int p = start + atomicAdd(&bincur[bin], 1);
        scratch[p] = v;
    }
    // P4: per-node cursor scatter (reads sorted order -> col per node ~src-ascending)
    for (int i = tid; i < nn; i += 512) lcur[i] = rp[n0 + i];
    __syncthreads();
    for (int e = start + tid; e < end; e += 512) {
        uint v = scratch[e];
        int doff = v >> 20;
        int s = v & 0xFFFFF;
        int pos = atomicAdd(&lcur[doff], 1);
        col[pos] = s;
    }
}

// ---------------- casts / transposes ----------------

__global__ void cast_f32_bf16(const float* __restrict__ src, ushort* __restrict__ dst, int n4) {
    int i = blockIdx.x * blockDim.x + threadIdx.x;
    if (i < n4) {
        float4 v = ((const float4*)src)[i];
        ushort4 o;
        o.x = f2bf(v.x); o.y = f2bf(v.y); o.z = f2bf(v.z); o.w = f2bf(v.w);
        ((ushort4*)dst)[i] = o;
    }
}

// src[K][N] fp32 -> dst[Npad][Kpad] bf16 (zero padded)
__global__ void transpose_cast(const float* __restrict__ src, ushort* __restrict__ dst,
                               int K, int N, int Kpad, int Npad) {
    int idx = blockIdx.x * blockDim.x + threadIdx.x;
    if (idx >= Npad * Kpad) return;
    int n = idx / Kpad, k = idx - n * Kpad;
    float v = (n < N && k < K) ? src[(size_t)k * N + n] : 0.0f;
    dst[idx] = f2bf(v);
}

// ---------------- aggregation (gather over CSR, bf16 rows, fp32 accum) ----------------
// Y[n] = 2*dinv[n]^2 * X[n] + sum_{e in in(n)} dinv[src]*dinv[n] * X[src]
// Split-wave wide gathers (R4 form). Edge lists are ~src-sorted (bucket_scatter),
// so concurrent waves walk X in quantile-aligned windows for L2 locality.

// D = 128 bf16 (256B rows = 16 uint4): 4 groups of 16 lanes, 4 rows/load
__global__ void aggregate128(const ushort* __restrict__ X, ushort* __restrict__ Y,
                             const int* __restrict__ rp, const int* __restrict__ col,
                             const float* __restrict__ dinv, int N) {
    int gw = blockIdx.x * (blockDim.x >> 6) + (threadIdx.x >> 6);
    int lane = threadIdx.x & 63;
    if (gw >= N) return;
    int g = lane >> 4;        // edge parity class 0..3
    int sub = lane & 15;      // uint4 index within row
    float di = dinv[gw];
    float sc = 2.0f * di * di;
    const uint4* Xr = (const uint4*)X;   // row stride = 16 uint4
    float a[8] = {};
    if (g == 0) acc8(a, Xr[(size_t)gw * 16 + sub], sc);   // self term
    int e = rp[gw], end = rp[gw + 1];
    int base = e;
    for (; base + 8 <= end; base += 8) {
        int c0 = col[base + g];
        int c1 = col[base + 4 + g];
        float w0 = dinv[c0] * di, w1 = dinv[c1] * di;
        uint4 v0 = Xr[(size_t)c0 * 16 + sub];
        uint4 v1 = Xr[(size_t)c1 * 16 + sub];
        acc8(a, v0, w0);
        acc8(a, v1, w1);
    }
    if (base + 4 <= end) {
        int c0 = col[base + g];
        float w0 = dinv[c0] * di;
        acc8(a, Xr[(size_t)c0 * 16 + sub], w0);
        base += 4;
    }
    int rem = end - base;    // 0..3
    if (g < rem) {
        int c0 = col[base + g];
        float w0 = dinv[c0] * di;
        acc8(a, Xr[(size_t)c0 * 16 + sub], w0);
    }
    #pragma unroll
    for (int q = 0; q < 8; ++q) {
        a[q] += __shfl_xor(a[q], 16);
        a[q] += __shfl_xor(a[q], 32);
    }
    if (g == 0) {
        uint4 o;
        o.x = packbf2(a[0], a[1]);
        o.y = packbf2(a[2], a[3]);
        o.z = packbf2(a[4], a[5]);
        o.w = packbf2(a[6], a[7]);
        ((uint4*)Y)[(size_t)gw * 16 + sub] = o;
    }
}

// D = 256 bf16 (512B rows = 32 uint4): 2 groups of 32 lanes, 2 rows/load
__global__ void aggregate256(const ushort* __restrict__ X, ushort* __restrict__ Y,
                             const int* __restrict__ rp, const int* __restrict__ col,
                             const float* __restrict__ dinv, int N) {
    int gw = blockIdx.x * (blockDim.x >> 6) + (threadIdx.x >> 6);
    int lane = threadIdx.x & 63;
    if (gw >= N) return;
    int g = lane >> 5;        // edge parity class 0..1
    int sub = lane & 31;      // uint4 index within row
    float di = dinv[gw];
    float sc = 2.0f * di * di;
    const uint4* Xr = (const uint4*)X;   // row stride = 32 uint4
    float a[8] = {};
    if (g == 0) acc8(a, Xr[(size_t)gw * 32 + sub], sc);   // self term
    int e = rp[gw], end = rp[gw + 1];
    int base = e;
    for (; base + 4 <= end; base += 4) {
        int c0 = col[base + g];
        int c1 = col[base + 2 + g];
        float w0 = dinv[c0] * di, w1 = dinv[c1] * di;
        uint4 v0 = Xr[(size_t)c0 * 32 + sub];
        uint4 v1 = Xr[(size_t)c1 * 32 + sub];
        acc8(a, v0, w0);
        acc8(a, v1, w1);
    }
    if (base + 2 <= end) {
        int c0 = col[base + g];
        float w0 = dinv[c0] * di;
        acc8(a, Xr[(size_t)c0 * 32 + sub], w0);
        base += 2;
    }
    if (base < end && g == 0) {   // one leftover edge
        int c0 = col[base];
        float w0 = dinv[c0] * di;
        acc8(a, Xr[(size_t)c0 * 32 + sub], w0);
    }
    #pragma unroll
    for (int q = 0; q < 8; ++q) a[q] += __shfl_xor(a[q], 32);
    if (g == 0) {
        uint4 o;
        o.x = packbf2(a[0], a[1]);
        o.y = packbf2(a[2], a[3]);
        o.z = packbf2(a[4], a[5]);
        o.w = packbf2(a[6], a[7]);
        ((uint4*)Y)[(size_t)gw * 32 + sub] = o;
    }
}

// ---------------- bf16 MFMA GEMM (m97 structure) ----------------
// C[M,Nact] = epi(A[M,K]_bf16 @ BT[Npad,K]_bf16^T + bias)
// BM=128, BN=128, BK=32, 256 threads = 4 waves, each wave 64x64 (4x4 MFMA tiles)
// MODE 0: relu -> bf16 store
// MODE 2: plain -> f32 store
// MODE 3: softplus -> f32 store (Cout) AND tanh(sp*softplus) -> bf16 store (C2,
//         ld 512, cols [Nact,512) zeroed) — feeds the head GEMM.
// NOTE: plain (cached) stores on purpose — R5 showed nontemporal stores break
// L2 write-combining of the 64B epilogue segments (+22% WRITE_SIZE, +50us).

template<int K, int MODE>
__global__ __launch_bounds__(256)
void gemm_bt(const ushort* __restrict__ A, const ushort* __restrict__ BT,
             const float* __restrict__ bias, void* __restrict__ Cout,
             int M, int Nact, int ldc, ushort* __restrict__ C2,
             const float* __restrict__ thr) {
    __shared__ ushort sA[128 * 32];
    __shared__ ushort sB[128 * 32];
    int tid = threadIdx.x;
    int lane = tid & 63;
    int w = tid >> 6;
    int wr = w >> 1, wc = w & 1;
    int row0 = blockIdx.y * 128;
    int col0 = blockIdx.x * 128;
    float sp = 0.0f;
    if (MODE == 3) sp = softplus_fast(*thr);
    f32x4 acc[4][4] = {};

    for (int kt = 0; kt < K; kt += 32) {
        if (kt) __syncthreads();
        #pragma unroll
        for (int L = 0; L < 2; ++L) {
            int cb = L * 256 + w * 64;
            int c = cb + lane;
            int r = c >> 2;
            int ko = (c & 3) * 8;
            int rr = min(row0 + r, M - 1);
            async_copy16(A + (size_t)rr * K + kt + ko, sA + (size_t)cb * 8);
        }
        #pragma unroll
        for (int L = 0; L < 2; ++L) {
            int cb = L * 256 + w * 64;
            int c = cb + lane;
            int nr = c >> 2;
            int ko = (c & 3) * 8;
            async_copy16(BT + (size_t)(col0 + nr) * K + kt + ko, sB + (size_t)cb * 8);
        }
        __syncthreads();
        bf16x8 af[4], bfr[4];
        #pragma unroll
        for (int i = 0; i < 4; ++i) {
            int row = wr * 64 + i * 16 + (lane & 15);
            af[i] = *(const bf16x8*)(sA + row * 32 + (lane >> 4) * 8);
        }
        #pragma unroll
        for (int j = 0; j < 4; ++j) {
            int n = wc * 64 + j * 16 + (lane & 15);
            bfr[j] = *(const bf16x8*)(sB + n * 32 + (lane >> 4) * 8);
        }
        #pragma unroll
        for (int i = 0; i < 4; ++i)
            #pragma unroll
            for (int j = 0; j < 4; ++j)
                acc[i][j] = __builtin_amdgcn_mfma_f32_16x16x32_bf16(af[i], bfr[j], acc[i][j], 0, 0, 0);
    }

    #pragma unroll
    for (int i = 0; i < 4; ++i) {
        #pragma unroll
        for (int j = 0; j < 4; ++j) {
            int col = col0 + wc * 64 + j * 16 + (lane & 15);
            if (MODE == 3) {
                bool act = (col < Nact);
                float bv = act ? bias[col] : 0.0f;
                #pragma unroll
                for (int r = 0; r < 4; ++r) {
                    int row = row0 + wr * 64 + i * 16 + (lane >> 4) * 4 + r;
                    if (row >= M) continue;
                    if (act) {
                        float v = softplus_fast(acc[i][j][r] + bv);
                        ((float*)Cout)[(size_t)row * ldc + col] = v;
                        C2[(size_t)row * 512 + col] = f2bf(tanh_fast(sp * v));
                    } else {
                        C2[(size_t)row * 512 + col] = 0;
                    }
                }
            } else {
                if (col >= Nact) continue;
                float bv = bias[col];
                #pragma unroll
                for (int r = 0; r < 4; ++r) {
                    int row = row0 + wr * 64 + i * 16 + (lane >> 4) * 4 + r;
                    if (row >= M) continue;
                    float v = acc[i][j][r] + bv;
                    if (MODE == 0) {
                        v = fmaxf(v, 0.0f);
                        ((ushort*)Cout)[(size_t)row * ldc + col] = f2bf(v);
                    } else {
                        ((float*)Cout)[(size_t)row * ldc + col] = v;
                    }
                }
            }
        }
    }
}

// ---------------- launch ----------------

extern "C" void kernel_launch(void* const* d_in, const int* in_sizes, int n_in,
                              void* d_out, int out_size, void* d_ws, size_t ws_size,
                              hipStream_t stream) {
    const float* x    = (const float*)d_in[0];
    const int*   ei   = (const int*)d_in[1];
    const float* W1   = (const float*)d_in[2];
    const float* b1   = (const float*)d_in[3];
    const float* W2   = (const float*)d_in[4];
    const float* b2   = (const float*)d_in[5];
    const float* Wout = (const float*)d_in[6];
    const float* bout = (const float*)d_in[7];
    const float* thr  = (const float*)d_in[8];

    int N = in_sizes[0] / DIN;
    int E = in_sizes[1] / 2;
    const int* srcI = ei;
    const int* dstI = ei + E;

    char* wsp = (char*)d_ws;
    size_t o = 0;
    auto alloc = [&](size_t bytes) -> void* {
        void* p = wsp + o;
        o = (o + bytes + 255) & ~(size_t)255;
        return p;
    };
    int*    deg   = (int*)alloc((size_t)N * 4);
    float*  dinv  = (float*)alloc((size_t)N * 4);
    int*    rp    = (int*)alloc((size_t)(N + 1) * 4);
    int*    bsum  = (int*)alloc(1024);
    int*    bcur  = (int*)alloc(MAXB * 4);
    ushort* W1T   = (ushort*)alloc((size_t)256 * 128 * 2);
    ushort* W2T   = (ushort*)alloc((size_t)512 * 256 * 2);
    ushort* WoutT = (ushort*)alloc((size_t)128 * 512 * 2);
    ushort* bufA  = (ushort*)alloc((size_t)N * 256 * 2);  // scratch, then xbf+xa, later ha
    // col + hbuf live contiguously; after aggregate256 both are dead and the
    // region is reused as pbf [N,512] bf16 (tanh(sp*softplus) activations).
    size_t  col_off = o;
    int*    col   = (int*)alloc((size_t)E * 4);
    ushort* hbuf  = (ushort*)alloc((size_t)N * 256 * 2);  // h bf16 (pairBuf before gemm1)
    size_t  pbf_need = col_off + (size_t)N * 512 * 2;
    if (o < pbf_need) o = (pbf_need + 255) & ~(size_t)255;
    ushort* pbf = (ushort*)(wsp + col_off);               // [N,512] bf16

    ushort* xbf = bufA;                       // [N,128] bf16
    ushort* xa  = bufA + (size_t)N * 128;     // [N,128] bf16
    ushort* ha  = bufA;                       // [N,256] bf16 (reuses xbf+xa)
    uint* pairBuf = (uint*)hbuf;              // [E] packed edges (dead before gemm1 writes hbuf)
    uint* scratch = (uint*)bufA;              // [E] sort scratch (dead before cast writes xbf)

    float* mr   = (float*)d_out;                    // [N,500]
    float* yout = (float*)d_out + (size_t)N * MODD; // [N,100]

    int mtiles = (N + 127) / 128;
    int NB = (N + (1 << BSH) - 1) >> BSH;           // node-range buckets (196 for N=100K)

    // --- CSR build ---
    hipMemsetAsync(deg, 0, (size_t)N * 4, stream);
    count_deg<<<(E + 255) / 256, 256, 0, stream>>>(dstI, deg, E);
    compute_dinv<<<(N + 255) / 256, 256, 0, stream>>>(deg, dinv, N);
    int nb = (N + 1023) / 1024;
    scan_block<<<nb, 1024, 0, stream>>>(deg, rp, bsum, N);
    scan_bsums<<<1, 64, 0, stream>>>(bsum, nb);
    scan_add<<<(N + 256) / 256, 256, 0, stream>>>(rp, bsum, N, nb);
    // binned 2-pass edge scatter, with per-bucket src-bin sort
    init_bucket_cursor<<<1, 256, 0, stream>>>(rp, bcur, NB);
    partition_edges<<<(E + PCH - 1) / PCH, 256, 0, stream>>>(srcI, dstI, bcur, pairBuf, E, NB);
    bucket_scatter<<<NB, 512, 0, stream>>>(pairBuf, rp, col, scratch, N);

    // --- weight prep (cast AFTER bucket_scatter: xbf region doubles as sort scratch) ---
    cast_f32_bf16<<<((N * DIN / 4) + 255) / 256, 256, 0, stream>>>(x, xbf, N * DIN / 4);
    transpose_cast<<<(256 * 128 + 255) / 256, 256, 0, stream>>>(W1, W1T, 128, 256, 128, 256);
    transpose_cast<<<(512 * 256 + 255) / 256, 256, 0, stream>>>(W2, W2T, 256, 500, 256, 512);
    transpose_cast<<<(128 * 512 + 255) / 256, 256, 0, stream>>>(Wout, WoutT, 500, 100, 512, 128);

    // --- conv1 ---
    aggregate128<<<(N + 3) / 4, 256, 0, stream>>>(xbf, xa, rp, col, dinv, N);
    gemm_bt<128, 0><<<dim3(2, mtiles), 256, 0, stream>>>(xa, W1T, b1, hbuf, N, HID, HID,
                                                         nullptr, nullptr);

    // --- conv2 (epilogue also emits tanh(sp*softplus) bf16 into pbf) ---
    aggregate256<<<(N + 3) / 4, 256, 0, stream>>>(hbuf, ha, rp, col, dinv, N);
    gemm_bt<256, 3><<<dim3(4, mtiles), 256, 0, stream>>>(ha, W2T, b2, mr, N, MODD, MODD,
                                                         pbf, thr);

    // --- head: y = pbf @ Wout + bout ---
    gemm_bt<512, 2><<<dim3(1, mtiles), 256, 0, stream>>>(pbf, WoutT, bout, yout, N, OUTD, OUTD,
                                                         nullptr, nullptr);
}

// Round 7
// 959.268 us; speedup vs baseline: 1.2313x; 1.1505x over previous
//
#include <hip/hip_runtime.h>
#include <cstdint>
#include <cstddef>

#define DIN 128
#define HID 256
#define MODD 500
#define OUTD 100

typedef unsigned int uint;
typedef unsigned short ushort;
typedef __attribute__((ext_vector_type(8))) __bf16 bf16x8;
typedef __attribute__((ext_vector_type(4))) float f32x4;

__device__ __forceinline__ float bf2f(ushort u) {
    return __uint_as_float(((uint)u) << 16);
}
__device__ __forceinline__ ushort f2bf(float f) {
    uint u = __float_as_uint(f);
    return (ushort)((u + 0x7FFF + ((u >> 16) & 1)) >> 16);
}
__device__ __forceinline__ uint packbf2(float lo, float hi) {
    return (uint)f2bf(lo) | ((uint)f2bf(hi) << 16);
}
__device__ __forceinline__ void async_copy16(const void* g, void* l) {
    __builtin_amdgcn_global_load_lds((const __attribute__((address_space(1))) void*)g,
                                     (__attribute__((address_space(3))) void*)l, 16, 0, 0);
}
__device__ __forceinline__ float tanh_fast(float x) {
    // x >= 0 in our use (softplus output); stable both ends anyway
    return 1.0f - 2.0f / (__expf(2.0f * x) + 1.0f);
}
// stable fast softplus: max(v,0) + log(1 + exp(-|v|)); ~6 VALU ops vs libm's ~60+
__device__ __forceinline__ float softplus_fast(float v) {
    return fmaxf(v, 0.0f) + __logf(1.0f + __expf(-fabsf(v)));
}
// accumulate 8 bf16 (one uint4) scaled by w into a[0..8)
__device__ __forceinline__ void acc8(float* a, uint4 v, float w) {
    a[0] += w * bf2f((ushort)(v.x & 0xFFFF));
    a[1] += w * bf2f((ushort)(v.x >> 16));
    a[2] += w * bf2f((ushort)(v.y & 0xFFFF));
    a[3] += w * bf2f((ushort)(v.y >> 16));
    a[4] += w * bf2f((ushort)(v.z & 0xFFFF));
    a[5] += w * bf2f((ushort)(v.z >> 16));
    a[6] += w * bf2f((ushort)(v.w & 0xFFFF));
    a[7] += w * bf2f((ushort)(v.w >> 16));
}

// ---------------- binned CSR build ----------------
// Buckets of 512 consecutive dst nodes occupy contiguous CSR ranges.
// bucket_count: per-block LDS histogram of dst>>9 -> global bucket totals
//   (196 LDS bins; replaces count_deg's 3.2M random cross-XCD atomics).
// scan_buckets: trivial 196-entry scan -> bucket starts + partition cursors.
// partition_edges: scatter packed (src, dst-offset) records into bucket ranges.
// bucket_scatter: per-bucket LDS histogram over dst-offset gives node degrees;
//   512-wide scan gives per-node rp; writes rp, dinv, and the final col[] via
//   LDS cursors (random writes confined to an L2-resident window).
// NOTE: src-bin sorting inside buckets was tried (R5/R6) and measured null on
// the aggregate gather (FETCH 800->793MB) at +32us cost -> removed.
// Packing: src (<2^20) in low 20 bits, dst offset (<512) in bits 20..28.

#define BSH 9
#define MAXB 256
#define PCH 8192

__global__ __launch_bounds__(256)
void bucket_count(const int* __restrict__ dst, int* __restrict__ btot, int E, int NB) {
    __shared__ int hist[MAXB];
    int tid = threadIdx.x;
    int e0 = blockIdx.x * PCH;
    int e1 = min(e0 + PCH, E);
    for (int b = tid; b < MAXB; b += 256) hist[b] = 0;
    __syncthreads();
    for (int e = e0 + tid; e < e1; e += 256)
        atomicAdd(&hist[dst[e] >> BSH], 1);
    __syncthreads();
    for (int b = tid; b < NB; b += 256)
        if (hist[b]) atomicAdd(&btot[b], hist[b]);
}

__global__ void scan_buckets(const int* __restrict__ btot, int* __restrict__ bstart,
                             int* __restrict__ bcur, int* __restrict__ rp,
                             int NB, int N, int E) {
    if (threadIdx.x == 0 && blockIdx.x == 0) {
        int s = 0;
        for (int b = 0; b < NB; ++b) { bstart[b] = s; bcur[b] = s; s += btot[b]; }
        bstart[NB] = s;
        rp[N] = E;
    }
}

__global__ __launch_bounds__(256)
void partition_edges(const int* __restrict__ src, const int* __restrict__ dst,
                     int* __restrict__ bcur, uint* __restrict__ pairBuf,
                     int E, int NB) {
    __shared__ int hist[MAXB];
    __shared__ int gbase[MAXB];
    int tid = threadIdx.x;
    int e0 = blockIdx.x * PCH;
    int e1 = min(e0 + PCH, E);
    for (int b = tid; b < NB; b += 256) hist[b] = 0;
    __syncthreads();
    for (int e = e0 + tid; e < e1; e += 256) {
        int d = dst[e];
        atomicAdd(&hist[d >> BSH], 1);
    }
    __syncthreads();
    for (int b = tid; b < NB; b += 256) {
        int h = hist[b];
        gbase[b] = h ? atomicAdd(&bcur[b], h) : 0;
        hist[b] = 0;
    }
    __syncthreads();
    for (int e = e0 + tid; e < e1; e += 256) {
        int d = dst[e];
        int s = src[e];
        int b = d >> BSH;
        int idx = gbase[b] + atomicAdd(&hist[b], 1);
        pairBuf[idx] = (uint)s | ((uint)(d & ((1 << BSH) - 1)) << 20);
    }
}

// per-bucket: degrees from LDS hist -> rp + dinv + cursor scatter of col[]
__global__ __launch_bounds__(512)
void bucket_scatter(const uint* __restrict__ pairBuf, const int* __restrict__ bstart,
                    int* __restrict__ col, int* __restrict__ rp,
                    float* __restrict__ dinv, int N) {
    __shared__ int lcnt[1 << BSH];
    __shared__ int lcur[1 << BSH];
    __shared__ int wsum[8];
    int tid = threadIdx.x;
    int lane = tid & 63;
    int w = tid >> 6;
    int b = blockIdx.x;
    int n0 = b << BSH;
    int nn = min(1 << BSH, N - n0);
    int start = bstart[b];
    int end = bstart[b + 1];

    lcnt[tid] = 0;
    __syncthreads();
    for (int e = start + tid; e < end; e += 512)
        atomicAdd(&lcnt[pairBuf[e] >> 20], 1);
    __syncthreads();
    int cnt = lcnt[tid];
    // exclusive scan of 512 degrees (8 waves, shfl scan)
    int x = cnt;
    #pragma unroll
    for (int off = 1; off < 64; off <<= 1) {
        int t = __shfl_up(x, off);
        if (lane >= off) x += t;
    }
    if (lane == 63) wsum[w] = x;
    __syncthreads();
    if (tid == 0) {
        int s = 0;
        #pragma unroll
        for (int k = 0; k < 8; ++k) { int t = wsum[k]; wsum[k] = s; s += t; }
    }
    __syncthreads();
    int excl = start + wsum[w] + (x - cnt);
    if (tid < nn) {
        rp[n0 + tid] = excl;
        dinv[n0 + tid] = rsqrtf((float)cnt + 2.0f);
    }
    lcur[tid] = excl;
    __syncthreads();
    for (int e = start + tid; e < end; e += 512) {
        uint v = pairBuf[e];
        int pos = atomicAdd(&lcur[v >> 20], 1);
        col[pos] = (int)(v & 0xFFFFF);
    }
}

// ---------------- casts / transposes ----------------

__global__ void cast_f32_bf16(const float* __restrict__ src, ushort* __restrict__ dst, int n4) {
    int i = blockIdx.x * blockDim.x + threadIdx.x;
    if (i < n4) {
        float4 v = ((const float4*)src)[i];
        ushort4 o;
        o.x = f2bf(v.x); o.y = f2bf(v.y); o.z = f2bf(v.z); o.w = f2bf(v.w);
        ((ushort4*)dst)[i] = o;
    }
}

// src[K][N] fp32 -> dst[Npad][Kpad] bf16 (zero padded)
__global__ void transpose_cast(const float* __restrict__ src, ushort* __restrict__ dst,
                               int K, int N, int Kpad, int Npad) {
    int idx = blockIdx.x * blockDim.x + threadIdx.x;
    if (idx >= Npad * Kpad) return;
    int n = idx / Kpad, k = idx - n * Kpad;
    float v = (n < N && k < K) ? src[(size_t)k * N + n] : 0.0f;
    dst[idx] = f2bf(v);
}

// ---------------- aggregation (gather over CSR, bf16 rows, fp32 accum) ----------------
// Y[n] = 2*dinv[n]^2 * X[n] + sum_{e in in(n)} dinv[src]*dinv[n] * X[src]
// Split-wave wide gathers (R4 form — best measured). The gather is at the
// random-row L2-miss BW wall (~3.8 TB/s, 52% hit): deep MLP (R2), wider loads
// (R4), and src-sorting (R5/R6) all measured ~null. Do not restructure.

// D = 128 bf16 (256B rows = 16 uint4): 4 groups of 16 lanes, 4 rows/load
__global__ void aggregate128(const ushort* __restrict__ X, ushort* __restrict__ Y,
                             const int* __restrict__ rp, const int* __restrict__ col,
                             const float* __restrict__ dinv, int N) {
    int gw = blockIdx.x * (blockDim.x >> 6) + (threadIdx.x >> 6);
    int lane = threadIdx.x & 63;
    if (gw >= N) return;
    int g = lane >> 4;        // edge parity class 0..3
    int sub = lane & 15;      // uint4 index within row
    float di = dinv[gw];
    float sc = 2.0f * di * di;
    const uint4* Xr = (const uint4*)X;   // row stride = 16 uint4
    float a[8] = {};
    if (g == 0) acc8(a, Xr[(size_t)gw * 16 + sub], sc);   // self term
    int e = rp[gw], end = rp[gw + 1];
    int base = e;
    for (; base + 8 <= end; base += 8) {
        int c0 = col[base + g];
        int c1 = col[base + 4 + g];
        float w0 = dinv[c0] * di, w1 = dinv[c1] * di;
        uint4 v0 = Xr[(size_t)c0 * 16 + sub];
        uint4 v1 = Xr[(size_t)c1 * 16 + sub];
        acc8(a, v0, w0);
        acc8(a, v1, w1);
    }
    if (base + 4 <= end) {
        int c0 = col[base + g];
        float w0 = dinv[c0] * di;
        acc8(a, Xr[(size_t)c0 * 16 + sub], w0);
        base += 4;
    }
    int rem = end - base;    // 0..3
    if (g < rem) {
        int c0 = col[base + g];
        float w0 = dinv[c0] * di;
        acc8(a, Xr[(size_t)c0 * 16 + sub], w0);
    }
    #pragma unroll
    for (int q = 0; q < 8; ++q) {
        a[q] += __shfl_xor(a[q], 16);
        a[q] += __shfl_xor(a[q], 32);
    }
    if (g == 0) {
        uint4 o;
        o.x = packbf2(a[0], a[1]);
        o.y = packbf2(a[2], a[3]);
        o.z = packbf2(a[4], a[5]);
        o.w = packbf2(a[6], a[7]);
        ((uint4*)Y)[(size_t)gw * 16 + sub] = o;
    }
}

// D = 256 bf16 (512B rows = 32 uint4): 2 groups of 32 lanes, 2 rows/load
__global__ void aggregate256(const ushort* __restrict__ X, ushort* __restrict__ Y,
                             const int* __restrict__ rp, const int* __restrict__ col,
                             const float* __restrict__ dinv, int N) {
    int gw = blockIdx.x * (blockDim.x >> 6) + (threadIdx.x >> 6);
    int lane = threadIdx.x & 63;
    if (gw >= N) return;
    int g = lane >> 5;        // edge parity class 0..1
    int sub = lane & 31;      // uint4 index within row
    float di = dinv[gw];
    float sc = 2.0f * di * di;
    const uint4* Xr = (const uint4*)X;   // row stride = 32 uint4
    float a[8] = {};
    if (g == 0) acc8(a, Xr[(size_t)gw * 32 + sub], sc);   // self term
    int e = rp[gw], end = rp[gw + 1];
    int base = e;
    for (; base + 4 <= end; base += 4) {
        int c0 = col[base + g];
        int c1 = col[base + 2 + g];
        float w0 = dinv[c0] * di, w1 = dinv[c1] * di;
        uint4 v0 = Xr[(size_t)c0 * 32 + sub];
        uint4 v1 = Xr[(size_t)c1 * 32 + sub];
        acc8(a, v0, w0);
        acc8(a, v1, w1);
    }
    if (base + 2 <= end) {
        int c0 = col[base + g];
        float w0 = dinv[c0] * di;
        acc8(a, Xr[(size_t)c0 * 32 + sub], w0);
        base += 2;
    }
    if (base < end && g == 0) {   // one leftover edge
        int c0 = col[base];
        float w0 = dinv[c0] * di;
        acc8(a, Xr[(size_t)c0 * 32 + sub], w0);
    }
    #pragma unroll
    for (int q = 0; q < 8; ++q) a[q] += __shfl_xor(a[q], 32);
    if (g == 0) {
        uint4 o;
        o.x = packbf2(a[0], a[1]);
        o.y = packbf2(a[2], a[3]);
        o.z = packbf2(a[4], a[5]);
        o.w = packbf2(a[6], a[7]);
        ((uint4*)Y)[(size_t)gw * 32 + sub] = o;
    }
}

// ---------------- bf16 MFMA GEMM (m97 structure) ----------------
// C[M,Nact] = epi(A[M,K]_bf16 @ BT[Npad,K]_bf16^T + bias)
// BM=128, BN=128, BK=32, 256 threads = 4 waves, each wave 64x64 (4x4 MFMA tiles)
// MODE 0: relu -> bf16 store
// MODE 2: plain -> f32 store
// MODE 3: softplus -> f32 store (Cout) AND tanh(sp*softplus) -> bf16 store (C2,
//         ld 512, cols [Nact,512) zeroed) — feeds the head GEMM.
// NOTE: plain (cached) stores on purpose — R5 showed nontemporal stores break
// L2 write-combining of the 64B epilogue segments (+22% WRITE_SIZE, +50us).

template<int K, int MODE>
__global__ __launch_bounds__(256)
void gemm_bt(const ushort* __restrict__ A, const ushort* __restrict__ BT,
             const float* __restrict__ bias, void* __restrict__ Cout,
             int M, int Nact, int ldc, ushort* __restrict__ C2,
             const float* __restrict__ thr) {
    __shared__ ushort sA[128 * 32];
    __shared__ ushort sB[128 * 32];
    int tid = threadIdx.x;
    int lane = tid & 63;
    int w = tid >> 6;
    int wr = w >> 1, wc = w & 1;
    int row0 = blockIdx.y * 128;
    int col0 = blockIdx.x * 128;
    float sp = 0.0f;
    if (MODE == 3) sp = softplus_fast(*thr);
    f32x4 acc[4][4] = {};

    for (int kt = 0; kt < K; kt += 32) {
        if (kt) __syncthreads();
        #pragma unroll
        for (int L = 0; L < 2; ++L) {
            int cb = L * 256 + w * 64;
            int c = cb + lane;
            int r = c >> 2;
            int ko = (c & 3) * 8;
            int rr = min(row0 + r, M - 1);
            async_copy16(A + (size_t)rr * K + kt + ko, sA + (size_t)cb * 8);
        }
        #pragma unroll
        for (int L = 0; L < 2; ++L) {
            int cb = L * 256 + w * 64;
            int c = cb + lane;
            int nr = c >> 2;
            int ko = (c & 3) * 8;
            async_copy16(BT + (size_t)(col0 + nr) * K + kt + ko, sB + (size_t)cb * 8);
        }
        __syncthreads();
        bf16x8 af[4], bfr[4];
        #pragma unroll
        for (int i = 0; i < 4; ++i) {
            int row = wr * 64 + i * 16 + (lane & 15);
            af[i] = *(const bf16x8*)(sA + row * 32 + (lane >> 4) * 8);
        }
        #pragma unroll
        for (int j = 0; j < 4; ++j) {
            int n = wc * 64 + j * 16 + (lane & 15);
            bfr[j] = *(const bf16x8*)(sB + n * 32 + (lane >> 4) * 8);
        }
        #pragma unroll
        for (int i = 0; i < 4; ++i)
            #pragma unroll
            for (int j = 0; j < 4; ++j)
                acc[i][j] = __builtin_amdgcn_mfma_f32_16x16x32_bf16(af[i], bfr[j], acc[i][j], 0, 0, 0);
    }

    #pragma unroll
    for (int i = 0; i < 4; ++i) {
        #pragma unroll
        for (int j = 0; j < 4; ++j) {
            int col = col0 + wc * 64 + j * 16 + (lane & 15);
            if (MODE == 3) {
                bool act = (col < Nact);
                float bv = act ? bias[col] : 0.0f;
                #pragma unroll
                for (int r = 0; r < 4; ++r) {
                    int row = row0 + wr * 64 + i * 16 + (lane >> 4) * 4 + r;
                    if (row >= M) continue;
                    if (act) {
                        float v = softplus_fast(acc[i][j][r] + bv);
                        ((float*)Cout)[(size_t)row * ldc + col] = v;
                        C2[(size_t)row * 512 + col] = f2bf(tanh_fast(sp * v));
                    } else {
                        C2[(size_t)row * 512 + col] = 0;
                    }
                }
            } else {
                if (col >= Nact) continue;
                float bv = bias[col];
                #pragma unroll
                for (int r = 0; r < 4; ++r) {
                    int row = row0 + wr * 64 + i * 16 + (lane >> 4) * 4 + r;
                    if (row >= M) continue;
                    float v = acc[i][j][r] + bv;
                    if (MODE == 0) {
                        v = fmaxf(v, 0.0f);
                        ((ushort*)Cout)[(size_t)row * ldc + col] = f2bf(v);
                    } else {
                        ((float*)Cout)[(size_t)row * ldc + col] = v;
                    }
                }
            }
        }
    }
}

// ---------------- launch ----------------

extern "C" void kernel_launch(void* const* d_in, const int* in_sizes, int n_in,
                              void* d_out, int out_size, void* d_ws, size_t ws_size,
                              hipStream_t stream) {
    const float* x    = (const float*)d_in[0];
    const int*   ei   = (const int*)d_in[1];
    const float* W1   = (const float*)d_in[2];
    const float* b1   = (const float*)d_in[3];
    const float* W2   = (const float*)d_in[4];
    const float* b2   = (const float*)d_in[5];
    const float* Wout = (const float*)d_in[6];
    const float* bout = (const float*)d_in[7];
    const float* thr  = (const float*)d_in[8];

    int N = in_sizes[0] / DIN;
    int E = in_sizes[1] / 2;
    const int* srcI = ei;
    const int* dstI = ei + E;

    char* wsp = (char*)d_ws;
    size_t o = 0;
    auto alloc = [&](size_t bytes) -> void* {
        void* p = wsp + o;
        o = (o + bytes + 255) & ~(size_t)255;
        return p;
    };
    float*  dinv   = (float*)alloc((size_t)N * 4);
    int*    rp     = (int*)alloc((size_t)(N + 1) * 4);
    int*    btot   = (int*)alloc(MAXB * 4);
    int*    bstart = (int*)alloc((MAXB + 1) * 4);
    int*    bcur   = (int*)alloc(MAXB * 4);
    ushort* W1T    = (ushort*)alloc((size_t)256 * 128 * 2);
    ushort* W2T    = (ushort*)alloc((size_t)512 * 256 * 2);
    ushort* WoutT  = (ushort*)alloc((size_t)128 * 512 * 2);
    ushort* bufA   = (ushort*)alloc((size_t)N * 256 * 2);  // xbf+xa, later ha
    // col + hbuf live contiguously; after aggregate256 both are dead and the
    // region is reused as pbf [N,512] bf16 (tanh(sp*softplus) activations).
    size_t  col_off = o;
    int*    col   = (int*)alloc((size_t)E * 4);
    ushort* hbuf  = (ushort*)alloc((size_t)N * 256 * 2);  // h bf16 (pairBuf before gemm1)
    size_t  pbf_need = col_off + (size_t)N * 512 * 2;
    if (o < pbf_need) o = (pbf_need + 255) & ~(size_t)255;
    ushort* pbf = (ushort*)(wsp + col_off);               // [N,512] bf16

    ushort* xbf = bufA;                       // [N,128] bf16
    ushort* xa  = bufA + (size_t)N * 128;     // [N,128] bf16
    ushort* ha  = bufA;                       // [N,256] bf16 (reuses xbf+xa)
    uint* pairBuf = (uint*)hbuf;              // [E] packed edges (dead before gemm1 writes hbuf)

    float* mr   = (float*)d_out;                    // [N,500]
    float* yout = (float*)d_out + (size_t)N * MODD; // [N,100]

    int mtiles = (N + 127) / 128;
    int NB = (N + (1 << BSH) - 1) >> BSH;           // node-range buckets (196 for N=100K)

    // --- CSR build (fully binned; no per-node random atomics, no global scan) ---
    hipMemsetAsync(btot, 0, (size_t)NB * 4, stream);
    bucket_count<<<(E + PCH - 1) / PCH, 256, 0, stream>>>(dstI, btot, E, NB);
    scan_buckets<<<1, 64, 0, stream>>>(btot, bstart, bcur, rp, NB, N, E);
    partition_edges<<<(E + PCH - 1) / PCH, 256, 0, stream>>>(srcI, dstI, bcur, pairBuf, E, NB);
    bucket_scatter<<<NB, 512, 0, stream>>>(pairBuf, bstart, col, rp, dinv, N);

    // --- weight prep ---
    cast_f32_bf16<<<((N * DIN / 4) + 255) / 256, 256, 0, stream>>>(x, xbf, N * DIN / 4);
    transpose_cast<<<(256 * 128 + 255) / 256, 256, 0, stream>>>(W1, W1T, 128, 256, 128, 256);
    transpose_cast<<<(512 * 256 + 255) / 256, 256, 0, stream>>>(W2, W2T, 256, 500, 256, 512);
    transpose_cast<<<(128 * 512 + 255) / 256, 256, 0, stream>>>(Wout, WoutT, 500, 100, 512, 128);

    // --- conv1 ---
    aggregate128<<<(N + 3) / 4, 256, 0, stream>>>(xbf, xa, rp, col, dinv, N);
    gemm_bt<128, 0><<<dim3(2, mtiles), 256, 0, stream>>>(xa, W1T, b1, hbuf, N, HID, HID,
                                                         nullptr, nullptr);

    // --- conv2 (epilogue also emits tanh(sp*softplus) bf16 into pbf) ---
    aggregate256<<<(N + 3) / 4, 256, 0, stream>>>(hbuf, ha, rp, col, dinv, N);
    gemm_bt<256, 3><<<dim3(4, mtiles), 256, 0, stream>>>(ha, W2T, b2, mr, N, MODD, MODD,
                                                         pbf, thr);

    // --- head: y = pbf @ Wout + bout ---
    gemm_bt<512, 2><<<dim3(1, mtiles), 256, 0, stream>>>(pbf, WoutT, bout, yout, N, OUTD, OUTD,
                                                         nullptr, nullptr);
}

// Round 8
// 956.272 us; speedup vs baseline: 1.2351x; 1.0031x over previous
//
#include <hip/hip_runtime.h>
#include <cstdint>
#include <cstddef>

#define DIN 128
#define HID 256
#define MODD 500
#define OUTD 100

typedef unsigned int uint;
typedef unsigned short ushort;
typedef __attribute__((ext_vector_type(8))) __bf16 bf16x8;
typedef __attribute__((ext_vector_type(4))) float f32x4;

__device__ __forceinline__ float bf2f(ushort u) {
    return __uint_as_float(((uint)u) << 16);
}
__device__ __forceinline__ ushort f2bf(float f) {
    uint u = __float_as_uint(f);
    return (ushort)((u + 0x7FFF + ((u >> 16) & 1)) >> 16);
}
__device__ __forceinline__ uint packbf2(float lo, float hi) {
    return (uint)f2bf(lo) | ((uint)f2bf(hi) << 16);
}
__device__ __forceinline__ void async_copy16(const void* g, void* l) {
    __builtin_amdgcn_global_load_lds((const __attribute__((address_space(1))) void*)g,
                                     (__attribute__((address_space(3))) void*)l, 16, 0, 0);
}
__device__ __forceinline__ float tanh_fast(float x) {
    // x >= 0 in our use (softplus output); stable both ends anyway
    return 1.0f - 2.0f / (__expf(2.0f * x) + 1.0f);
}
// stable fast softplus: max(v,0) + log(1 + exp(-|v|)); ~6 VALU ops vs libm's ~60+
__device__ __forceinline__ float softplus_fast(float v) {
    return fmaxf(v, 0.0f) + __logf(1.0f + __expf(-fabsf(v)));
}
// accumulate 8 bf16 (one uint4) scaled by w into a[0..8)
__device__ __forceinline__ void acc8(float* a, uint4 v, float w) {
    a[0] += w * bf2f((ushort)(v.x & 0xFFFF));
    a[1] += w * bf2f((ushort)(v.x >> 16));
    a[2] += w * bf2f((ushort)(v.y & 0xFFFF));
    a[3] += w * bf2f((ushort)(v.y >> 16));
    a[4] += w * bf2f((ushort)(v.z & 0xFFFF));
    a[5] += w * bf2f((ushort)(v.z >> 16));
    a[6] += w * bf2f((ushort)(v.w & 0xFFFF));
    a[7] += w * bf2f((ushort)(v.w >> 16));
}

// ---------------- binned CSR build ----------------
// (R7 structure; verified. No per-node random atomics, no global scan.)
// Packing: src (<2^20) in low 20 bits, dst offset (<512) in bits 20..28.

#define BSH 9
#define MAXB 256
#define PCH 8192

__global__ __launch_bounds__(256)
void bucket_count(const int* __restrict__ dst, int* __restrict__ btot, int E, int NB) {
    __shared__ int hist[MAXB];
    int tid = threadIdx.x;
    int e0 = blockIdx.x * PCH;
    int e1 = min(e0 + PCH, E);
    for (int b = tid; b < MAXB; b += 256) hist[b] = 0;
    __syncthreads();
    for (int e = e0 + tid; e < e1; e += 256)
        atomicAdd(&hist[dst[e] >> BSH], 1);
    __syncthreads();
    for (int b = tid; b < NB; b += 256)
        if (hist[b]) atomicAdd(&btot[b], hist[b]);
}

__global__ void scan_buckets(const int* __restrict__ btot, int* __restrict__ bstart,
                             int* __restrict__ bcur, int* __restrict__ rp,
                             int NB, int N, int E) {
    if (threadIdx.x == 0 && blockIdx.x == 0) {
        int s = 0;
        for (int b = 0; b < NB; ++b) { bstart[b] = s; bcur[b] = s; s += btot[b]; }
        bstart[NB] = s;
        rp[N] = E;
    }
}

__global__ __launch_bounds__(256)
void partition_edges(const int* __restrict__ src, const int* __restrict__ dst,
                     int* __restrict__ bcur, uint* __restrict__ pairBuf,
                     int E, int NB) {
    __shared__ int hist[MAXB];
    __shared__ int gbase[MAXB];
    int tid = threadIdx.x;
    int e0 = blockIdx.x * PCH;
    int e1 = min(e0 + PCH, E);
    for (int b = tid; b < NB; b += 256) hist[b] = 0;
    __syncthreads();
    for (int e = e0 + tid; e < e1; e += 256) {
        int d = dst[e];
        atomicAdd(&hist[d >> BSH], 1);
    }
    __syncthreads();
    for (int b = tid; b < NB; b += 256) {
        int h = hist[b];
        gbase[b] = h ? atomicAdd(&bcur[b], h) : 0;
        hist[b] = 0;
    }
    __syncthreads();
    for (int e = e0 + tid; e < e1; e += 256) {
        int d = dst[e];
        int s = src[e];
        int b = d >> BSH;
        int idx = gbase[b] + atomicAdd(&hist[b], 1);
        pairBuf[idx] = (uint)s | ((uint)(d & ((1 << BSH) - 1)) << 20);
    }
}

// per-bucket: degrees from LDS hist -> rp + dinv + cursor scatter of col[]
__global__ __launch_bounds__(512)
void bucket_scatter(const uint* __restrict__ pairBuf, const int* __restrict__ bstart,
                    int* __restrict__ col, int* __restrict__ rp,
                    float* __restrict__ dinv, int N) {
    __shared__ int lcnt[1 << BSH];
    __shared__ int lcur[1 << BSH];
    __shared__ int wsum[8];
    int tid = threadIdx.x;
    int lane = tid & 63;
    int w = tid >> 6;
    int b = blockIdx.x;
    int n0 = b << BSH;
    int nn = min(1 << BSH, N - n0);
    int start = bstart[b];
    int end = bstart[b + 1];

    lcnt[tid] = 0;
    __syncthreads();
    for (int e = start + tid; e < end; e += 512)
        atomicAdd(&lcnt[pairBuf[e] >> 20], 1);
    __syncthreads();
    int cnt = lcnt[tid];
    // exclusive scan of 512 degrees (8 waves, shfl scan)
    int x = cnt;
    #pragma unroll
    for (int off = 1; off < 64; off <<= 1) {
        int t = __shfl_up(x, off);
        if (lane >= off) x += t;
    }
    if (lane == 63) wsum[w] = x;
    __syncthreads();
    if (tid == 0) {
        int s = 0;
        #pragma unroll
        for (int k = 0; k < 8; ++k) { int t = wsum[k]; wsum[k] = s; s += t; }
    }
    __syncthreads();
    int excl = start + wsum[w] + (x - cnt);
    if (tid < nn) {
        rp[n0 + tid] = excl;
        dinv[n0 + tid] = rsqrtf((float)cnt + 2.0f);
    }
    lcur[tid] = excl;
    __syncthreads();
    for (int e = start + tid; e < end; e += 512) {
        uint v = pairBuf[e];
        int pos = atomicAdd(&lcur[v >> 20], 1);
        col[pos] = (int)(v & 0xFFFFF);
    }
}

// ---------------- casts / transposes ----------------

__global__ void cast_f32_bf16(const float* __restrict__ src, ushort* __restrict__ dst, int n4) {
    int i = blockIdx.x * blockDim.x + threadIdx.x;
    if (i < n4) {
        float4 v = ((const float4*)src)[i];
        ushort4 o;
        o.x = f2bf(v.x); o.y = f2bf(v.y); o.z = f2bf(v.z); o.w = f2bf(v.w);
        ((ushort4*)dst)[i] = o;
    }
}

// src[K][N] fp32 -> dst[Npad][Kpad] bf16 (zero padded)
__global__ void transpose_cast(const float* __restrict__ src, ushort* __restrict__ dst,
                               int K, int N, int Kpad, int Npad) {
    int idx = blockIdx.x * blockDim.x + threadIdx.x;
    if (idx >= Npad * Kpad) return;
    int n = idx / Kpad, k = idx - n * Kpad;
    float v = (n < N && k < K) ? src[(size_t)k * N + n] : 0.0f;
    dst[idx] = f2bf(v);
}

// ---------------- aggregation (gather over CSR, bf16 rows, fp32 accum) ----------------
// Y[n] = 2*dinv[n]^2 * X[n] + sum_{e in in(n)} dinv[src]*dinv[n] * X[src]
// Split-wave wide gathers (R4 form — best measured). At the random-row gather
// wall (~3.76 TB/s, counters identical R4/R6/R7): deep MLP (R2), wider loads
// (R4), src-sorting (R5/R6) all ~null. DO NOT RESTRUCTURE.

// D = 128 bf16 (256B rows = 16 uint4): 4 groups of 16 lanes, 4 rows/load
__global__ void aggregate128(const ushort* __restrict__ X, ushort* __restrict__ Y,
                             const int* __restrict__ rp, const int* __restrict__ col,
                             const float* __restrict__ dinv, int N) {
    int gw = blockIdx.x * (blockDim.x >> 6) + (threadIdx.x >> 6);
    int lane = threadIdx.x & 63;
    if (gw >= N) return;
    int g = lane >> 4;        // edge parity class 0..3
    int sub = lane & 15;      // uint4 index within row
    float di = dinv[gw];
    float sc = 2.0f * di * di;
    const uint4* Xr = (const uint4*)X;   // row stride = 16 uint4
    float a[8] = {};
    if (g == 0) acc8(a, Xr[(size_t)gw * 16 + sub], sc);   // self term
    int e = rp[gw], end = rp[gw + 1];
    int base = e;
    for (; base + 8 <= end; base += 8) {
        int c0 = col[base + g];
        int c1 = col[base + 4 + g];
        float w0 = dinv[c0] * di, w1 = dinv[c1] * di;
        uint4 v0 = Xr[(size_t)c0 * 16 + sub];
        uint4 v1 = Xr[(size_t)c1 * 16 + sub];
        acc8(a, v0, w0);
        acc8(a, v1, w1);
    }
    if (base + 4 <= end) {
        int c0 = col[base + g];
        float w0 = dinv[c0] * di;
        acc8(a, Xr[(size_t)c0 * 16 + sub], w0);
        base += 4;
    }
    int rem = end - base;    // 0..3
    if (g < rem) {
        int c0 = col[base + g];
        float w0 = dinv[c0] * di;
        acc8(a, Xr[(size_t)c0 * 16 + sub], w0);
    }
    #pragma unroll
    for (int q = 0; q < 8; ++q) {
        a[q] += __shfl_xor(a[q], 16);
        a[q] += __shfl_xor(a[q], 32);
    }
    if (g == 0) {
        uint4 o;
        o.x = packbf2(a[0], a[1]);
        o.y = packbf2(a[2], a[3]);
        o.z = packbf2(a[4], a[5]);
        o.w = packbf2(a[6], a[7]);
        ((uint4*)Y)[(size_t)gw * 16 + sub] = o;
    }
}

// D = 256 bf16 (512B rows = 32 uint4): 2 groups of 32 lanes, 2 rows/load
__global__ void aggregate256(const ushort* __restrict__ X, ushort* __restrict__ Y,
                             const int* __restrict__ rp, const int* __restrict__ col,
                             const float* __restrict__ dinv, int N) {
    int gw = blockIdx.x * (blockDim.x >> 6) + (threadIdx.x >> 6);
    int lane = threadIdx.x & 63;
    if (gw >= N) return;
    int g = lane >> 5;        // edge parity class 0..1
    int sub = lane & 31;      // uint4 index within row
    float di = dinv[gw];
    float sc = 2.0f * di * di;
    const uint4* Xr = (const uint4*)X;   // row stride = 32 uint4
    float a[8] = {};
    if (g == 0) acc8(a, Xr[(size_t)gw * 32 + sub], sc);   // self term
    int e = rp[gw], end = rp[gw + 1];
    int base = e;
    for (; base + 4 <= end; base += 4) {
        int c0 = col[base + g];
        int c1 = col[base + 2 + g];
        float w0 = dinv[c0] * di, w1 = dinv[c1] * di;
        uint4 v0 = Xr[(size_t)c0 * 32 + sub];
        uint4 v1 = Xr[(size_t)c1 * 32 + sub];
        acc8(a, v0, w0);
        acc8(a, v1, w1);
    }
    if (base + 2 <= end) {
        int c0 = col[base + g];
        float w0 = dinv[c0] * di;
        acc8(a, Xr[(size_t)c0 * 32 + sub], w0);
        base += 2;
    }
    if (base < end && g == 0) {   // one leftover edge
        int c0 = col[base];
        float w0 = dinv[c0] * di;
        acc8(a, Xr[(size_t)c0 * 32 + sub], w0);
    }
    #pragma unroll
    for (int q = 0; q < 8; ++q) a[q] += __shfl_xor(a[q], 32);
    if (g == 0) {
        uint4 o;
        o.x = packbf2(a[0], a[1]);
        o.y = packbf2(a[2], a[3]);
        o.z = packbf2(a[4], a[5]);
        o.w = packbf2(a[6], a[7]);
        ((uint4*)Y)[(size_t)gw * 32 + sub] = o;
    }
}

// ---------------- bf16 MFMA GEMMs ----------------
// gemm_wide: 512 threads = 8 waves (2x4), BM=128, BN=256, BK=32.
//   Per-wave tile 64x64 (acc[4][4]) — same register layout as the 4-wave
//   version (VGPR ~80) so ~24 waves/CU resident vs ~10 before; conv2's A
//   re-reads drop 4x -> 2x, conv1's 2x -> 1x. LDS 24KB.
// gemm_bt: original 256-thread BN=128 version, kept for the head GEMM.
// MODE 0: relu -> bf16 store
// MODE 2: plain -> f32 store
// MODE 3: softplus -> f32 store (Cout) AND tanh(sp*softplus) -> bf16 store (C2,
//         ld 512, cols [Nact,512) zeroed) — feeds the head GEMM.
// NOTE: plain (cached) stores on purpose — R5 showed nontemporal stores break
// L2 write-combining of the 64B epilogue segments (+22% WRITE_SIZE, +50us).

template<int K, int MODE>
__global__ __launch_bounds__(512)
void gemm_wide(const ushort* __restrict__ A, const ushort* __restrict__ BT,
               const float* __restrict__ bias, void* __restrict__ Cout,
               int M, int Nact, int ldc, ushort* __restrict__ C2,
               const float* __restrict__ thr) {
    __shared__ ushort sA[128 * 32];
    __shared__ ushort sB[256 * 32];
    int tid = threadIdx.x;
    int lane = tid & 63;
    int w = tid >> 6;
    int wr = w >> 2, wc = w & 3;
    int row0 = blockIdx.y * 128;
    int col0 = blockIdx.x * 256;
    float sp = 0.0f;
    if (MODE == 3) sp = softplus_fast(*thr);
    f32x4 acc[4][4] = {};

    for (int kt = 0; kt < K; kt += 32) {
        if (kt) __syncthreads();
        // sA: 8KB = 512 x 16B -> one async copy per thread
        {
            int r = tid >> 2;
            int ko = (tid & 3) * 8;
            int rr = min(row0 + r, M - 1);
            async_copy16(A + (size_t)rr * K + kt + ko, sA + (size_t)tid * 8);
        }
        // sB: 16KB = 1024 x 16B -> two async copies per thread
        #pragma unroll
        for (int L = 0; L < 2; ++L) {
            int c = L * 512 + tid;
            int nr = c >> 2;
            int ko = (c & 3) * 8;
            async_copy16(BT + (size_t)(col0 + nr) * K + kt + ko, sB + (size_t)c * 8);
        }
        __syncthreads();
        bf16x8 af[4], bfr[4];
        #pragma unroll
        for (int i = 0; i < 4; ++i) {
            int row = wr * 64 + i * 16 + (lane & 15);
            af[i] = *(const bf16x8*)(sA + row * 32 + (lane >> 4) * 8);
        }
        #pragma unroll
        for (int j = 0; j < 4; ++j) {
            int n = wc * 64 + j * 16 + (lane & 15);
            bfr[j] = *(const bf16x8*)(sB + n * 32 + (lane >> 4) * 8);
        }
        #pragma unroll
        for (int i = 0; i < 4; ++i)
            #pragma unroll
            for (int j = 0; j < 4; ++j)
                acc[i][j] = __builtin_amdgcn_mfma_f32_16x16x32_bf16(af[i], bfr[j], acc[i][j], 0, 0, 0);
    }

    #pragma unroll
    for (int i = 0; i < 4; ++i) {
        #pragma unroll
        for (int j = 0; j < 4; ++j) {
            int col = col0 + wc * 64 + j * 16 + (lane & 15);
            if (MODE == 3) {
                bool act = (col < Nact);
                float bv = act ? bias[col] : 0.0f;
                #pragma unroll
                for (int r = 0; r < 4; ++r) {
                    int row = row0 + wr * 64 + i * 16 + (lane >> 4) * 4 + r;
                    if (row >= M) continue;
                    if (act) {
                        float v = softplus_fast(acc[i][j][r] + bv);
                        ((float*)Cout)[(size_t)row * ldc + col] = v;
                        C2[(size_t)row * 512 + col] = f2bf(tanh_fast(sp * v));
                    } else {
                        C2[(size_t)row * 512 + col] = 0;
                    }
                }
            } else {
                if (col >= Nact) continue;
                float bv = bias[col];
                #pragma unroll
                for (int r = 0; r < 4; ++r) {
                    int row = row0 + wr * 64 + i * 16 + (lane >> 4) * 4 + r;
                    if (row >= M) continue;
                    float v = acc[i][j][r] + bv;
                    if (MODE == 0) {
                        v = fmaxf(v, 0.0f);
                        ((ushort*)Cout)[(size_t)row * ldc + col] = f2bf(v);
                    } else {
                        ((float*)Cout)[(size_t)row * ldc + col] = v;
                    }
                }
            }
        }
    }
}

template<int K, int MODE>
__global__ __launch_bounds__(256)
void gemm_bt(const ushort* __restrict__ A, const ushort* __restrict__ BT,
             const float* __restrict__ bias, void* __restrict__ Cout,
             int M, int Nact, int ldc) {
    __shared__ ushort sA[128 * 32];
    __shared__ ushort sB[128 * 32];
    int tid = threadIdx.x;
    int lane = tid & 63;
    int w = tid >> 6;
    int wr = w >> 1, wc = w & 1;
    int row0 = blockIdx.y * 128;
    int col0 = blockIdx.x * 128;
    f32x4 acc[4][4] = {};

    for (int kt = 0; kt < K; kt += 32) {
        if (kt) __syncthreads();
        #pragma unroll
        for (int L = 0; L < 2; ++L) {
            int cb = L * 256 + w * 64;
            int c = cb + lane;
            int r = c >> 2;
            int ko = (c & 3) * 8;
            int rr = min(row0 + r, M - 1);
            async_copy16(A + (size_t)rr * K + kt + ko, sA + (size_t)cb * 8);
        }
        #pragma unroll
        for (int L = 0; L < 2; ++L) {
            int cb = L * 256 + w * 64;
            int c = cb + lane;
            int nr = c >> 2;
            int ko = (c & 3) * 8;
            async_copy16(BT + (size_t)(col0 + nr) * K + kt + ko, sB + (size_t)cb * 8);
        }
        __syncthreads();
        bf16x8 af[4], bfr[4];
        #pragma unroll
        for (int i = 0; i < 4; ++i) {
            int row = wr * 64 + i * 16 + (lane & 15);
            af[i] = *(const bf16x8*)(sA + row * 32 + (lane >> 4) * 8);
        }
        #pragma unroll
        for (int j = 0; j < 4; ++j) {
            int n = wc * 64 + j * 16 + (lane & 15);
            bfr[j] = *(const bf16x8*)(sB + n * 32 + (lane >> 4) * 8);
        }
        #pragma unroll
        for (int i = 0; i < 4; ++i)
            #pragma unroll
            for (int j = 0; j < 4; ++j)
                acc[i][j] = __builtin_amdgcn_mfma_f32_16x16x32_bf16(af[i], bfr[j], acc[i][j], 0, 0, 0);
    }

    #pragma unroll
    for (int i = 0; i < 4; ++i) {
        #pragma unroll
        for (int j = 0; j < 4; ++j) {
            int col = col0 + wc * 64 + j * 16 + (lane & 15);
            if (col >= Nact) continue;
            float bv = bias[col];
            #pragma unroll
            for (int r = 0; r < 4; ++r) {
                int row = row0 + wr * 64 + i * 16 + (lane >> 4) * 4 + r;
                if (row >= M) continue;
                float v = acc[i][j][r] + bv;
                if (MODE == 0) {
                    v = fmaxf(v, 0.0f);
                    ((ushort*)Cout)[(size_t)row * ldc + col] = f2bf(v);
                } else {
                    ((float*)Cout)[(size_t)row * ldc + col] = v;
                }
            }
        }
    }
}

// ---------------- launch ----------------

extern "C" void kernel_launch(void* const* d_in, const int* in_sizes, int n_in,
                              void* d_out, int out_size, void* d_ws, size_t ws_size,
                              hipStream_t stream) {
    const float* x    = (const float*)d_in[0];
    const int*   ei   = (const int*)d_in[1];
    const float* W1   = (const float*)d_in[2];
    const float* b1   = (const float*)d_in[3];
    const float* W2   = (const float*)d_in[4];
    const float* b2   = (const float*)d_in[5];
    const float* Wout = (const float*)d_in[6];
    const float* bout = (const float*)d_in[7];
    const float* thr  = (const float*)d_in[8];

    int N = in_sizes[0] / DIN;
    int E = in_sizes[1] / 2;
    const int* srcI = ei;
    const int* dstI = ei + E;

    char* wsp = (char*)d_ws;
    size_t o = 0;
    auto alloc = [&](size_t bytes) -> void* {
        void* p = wsp + o;
        o = (o + bytes + 255) & ~(size_t)255;
        return p;
    };
    float*  dinv   = (float*)alloc((size_t)N * 4);
    int*    rp     = (int*)alloc((size_t)(N + 1) * 4);
    int*    btot   = (int*)alloc(MAXB * 4);
    int*    bstart = (int*)alloc((MAXB + 1) * 4);
    int*    bcur   = (int*)alloc(MAXB * 4);
    ushort* W1T    = (ushort*)alloc((size_t)256 * 128 * 2);
    ushort* W2T    = (ushort*)alloc((size_t)512 * 256 * 2);
    ushort* WoutT  = (ushort*)alloc((size_t)128 * 512 * 2);
    ushort* bufA   = (ushort*)alloc((size_t)N * 256 * 2);  // xbf+xa, later ha
    // col + hbuf live contiguously; after aggregate256 both are dead and the
    // region is reused as pbf [N,512] bf16 (tanh(sp*softplus) activations).
    size_t  col_off = o;
    int*    col   = (int*)alloc((size_t)E * 4);
    ushort* hbuf  = (ushort*)alloc((size_t)N * 256 * 2);  // h bf16 (pairBuf before gemm1)
    size_t  pbf_need = col_off + (size_t)N * 512 * 2;
    if (o < pbf_need) o = (pbf_need + 255) & ~(size_t)255;
    ushort* pbf = (ushort*)(wsp + col_off);               // [N,512] bf16

    ushort* xbf = bufA;                       // [N,128] bf16
    ushort* xa  = bufA + (size_t)N * 128;     // [N,128] bf16
    ushort* ha  = bufA;                       // [N,256] bf16 (reuses xbf+xa)
    uint* pairBuf = (uint*)hbuf;              // [E] packed edges (dead before gemm1 writes hbuf)

    float* mr   = (float*)d_out;                    // [N,500]
    float* yout = (float*)d_out + (size_t)N * MODD; // [N,100]

    int mtiles = (N + 127) / 128;
    int NB = (N + (1 << BSH) - 1) >> BSH;           // node-range buckets (196 for N=100K)

    // --- CSR build (fully binned; no per-node random atomics, no global scan) ---
    hipMemsetAsync(btot, 0, (size_t)NB * 4, stream);
    bucket_count<<<(E + PCH - 1) / PCH, 256, 0, stream>>>(dstI, btot, E, NB);
    scan_buckets<<<1, 64, 0, stream>>>(btot, bstart, bcur, rp, NB, N, E);
    partition_edges<<<(E + PCH - 1) / PCH, 256, 0, stream>>>(srcI, dstI, bcur, pairBuf, E, NB);
    bucket_scatter<<<NB, 512, 0, stream>>>(pairBuf, bstart, col, rp, dinv, N);

    // --- weight prep ---
    cast_f32_bf16<<<((N * DIN / 4) + 255) / 256, 256, 0, stream>>>(x, xbf, N * DIN / 4);
    transpose_cast<<<(256 * 128 + 255) / 256, 256, 0, stream>>>(W1, W1T, 128, 256, 128, 256);
    transpose_cast<<<(512 * 256 + 255) / 256, 256, 0, stream>>>(W2, W2T, 256, 500, 256, 512);
    transpose_cast<<<(128 * 512 + 255) / 256, 256, 0, stream>>>(Wout, WoutT, 500, 100, 512, 128);

    // --- conv1 (BN=256 covers all 256 cols: A read once) ---
    aggregate128<<<(N + 3) / 4, 256, 0, stream>>>(xbf, xa, rp, col, dinv, N);
    gemm_wide<128, 0><<<dim3(1, mtiles), 512, 0, stream>>>(xa, W1T, b1, hbuf, N, HID, HID,
                                                           nullptr, nullptr);

    // --- conv2 (2 col-tiles of 256; epilogue emits tanh bf16 into pbf) ---
    aggregate256<<<(N + 3) / 4, 256, 0, stream>>>(hbuf, ha, rp, col, dinv, N);
    gemm_wide<256, 3><<<dim3(2, mtiles), 512, 0, stream>>>(ha, W2T, b2, mr, N, MODD, MODD,
                                                           pbf, thr);

    // --- head: y = pbf @ Wout + bout ---
    gemm_bt<512, 2><<<dim3(1, mtiles), 256, 0, stream>>>(pbf, WoutT, bout, yout, N, OUTD, OUTD);
}

// Round 9
// 955.162 us; speedup vs baseline: 1.2366x; 1.0012x over previous
//
#include <hip/hip_runtime.h>
#include <cstdint>
#include <cstddef>

#define DIN 128
#define HID 256
#define MODD 500
#define OUTD 100

typedef unsigned int uint;
typedef unsigned short ushort;
typedef __attribute__((ext_vector_type(8))) __bf16 bf16x8;
typedef __attribute__((ext_vector_type(4))) float f32x4;

__device__ __forceinline__ float bf2f(ushort u) {
    return __uint_as_float(((uint)u) << 16);
}
__device__ __forceinline__ ushort f2bf(float f) {
    uint u = __float_as_uint(f);
    return (ushort)((u + 0x7FFF + ((u >> 16) & 1)) >> 16);
}
__device__ __forceinline__ uint packbf2(float lo, float hi) {
    return (uint)f2bf(lo) | ((uint)f2bf(hi) << 16);
}
__device__ __forceinline__ void async_copy16(const void* g, void* l) {
    __builtin_amdgcn_global_load_lds((const __attribute__((address_space(1))) void*)g,
                                     (__attribute__((address_space(3))) void*)l, 16, 0, 0);
}
__device__ __forceinline__ float tanh_fast(float x) {
    // x >= 0 in our use (softplus output); stable both ends anyway
    return 1.0f - 2.0f / (__expf(2.0f * x) + 1.0f);
}
// stable fast softplus: max(v,0) + log(1 + exp(-|v|)); ~6 VALU ops vs libm's ~60+
__device__ __forceinline__ float softplus_fast(float v) {
    return fmaxf(v, 0.0f) + __logf(1.0f + __expf(-fabsf(v)));
}
// accumulate 8 bf16 (one uint4) scaled by w into a[0..8)
__device__ __forceinline__ void acc8(float* a, uint4 v, float w) {
    a[0] += w * bf2f((ushort)(v.x & 0xFFFF));
    a[1] += w * bf2f((ushort)(v.x >> 16));
    a[2] += w * bf2f((ushort)(v.y & 0xFFFF));
    a[3] += w * bf2f((ushort)(v.y >> 16));
    a[4] += w * bf2f((ushort)(v.z & 0xFFFF));
    a[5] += w * bf2f((ushort)(v.z >> 16));
    a[6] += w * bf2f((ushort)(v.w & 0xFFFF));
    a[7] += w * bf2f((ushort)(v.w >> 16));
}

// ---------------- binned CSR build ----------------
// (R7 structure; verified. No per-node random atomics, no global scan.)
// Packing: src (<2^20) in low 20 bits, dst offset (<512) in bits 20..28.

#define BSH 9
#define MAXB 256
#define PCH 8192

__global__ __launch_bounds__(256)
void bucket_count(const int* __restrict__ dst, int* __restrict__ btot, int E, int NB) {
    __shared__ int hist[MAXB];
    int tid = threadIdx.x;
    int e0 = blockIdx.x * PCH;
    int e1 = min(e0 + PCH, E);
    for (int b = tid; b < MAXB; b += 256) hist[b] = 0;
    __syncthreads();
    for (int e = e0 + tid; e < e1; e += 256)
        atomicAdd(&hist[dst[e] >> BSH], 1);
    __syncthreads();
    for (int b = tid; b < NB; b += 256)
        if (hist[b]) atomicAdd(&btot[b], hist[b]);
}

__global__ void scan_buckets(const int* __restrict__ btot, int* __restrict__ bstart,
                             int* __restrict__ bcur, int* __restrict__ rp,
                             int NB, int N, int E) {
    if (threadIdx.x == 0 && blockIdx.x == 0) {
        int s = 0;
        for (int b = 0; b < NB; ++b) { bstart[b] = s; bcur[b] = s; s += btot[b]; }
        bstart[NB] = s;
        rp[N] = E;
    }
}

__global__ __launch_bounds__(256)
void partition_edges(const int* __restrict__ src, const int* __restrict__ dst,
                     int* __restrict__ bcur, uint* __restrict__ pairBuf,
                     int E, int NB) {
    __shared__ int hist[MAXB];
    __shared__ int gbase[MAXB];
    int tid = threadIdx.x;
    int e0 = blockIdx.x * PCH;
    int e1 = min(e0 + PCH, E);
    for (int b = tid; b < NB; b += 256) hist[b] = 0;
    __syncthreads();
    for (int e = e0 + tid; e < e1; e += 256) {
        int d = dst[e];
        atomicAdd(&hist[d >> BSH], 1);
    }
    __syncthreads();
    for (int b = tid; b < NB; b += 256) {
        int h = hist[b];
        gbase[b] = h ? atomicAdd(&bcur[b], h) : 0;
        hist[b] = 0;
    }
    __syncthreads();
    for (int e = e0 + tid; e < e1; e += 256) {
        int d = dst[e];
        int s = src[e];
        int b = d >> BSH;
        int idx = gbase[b] + atomicAdd(&hist[b], 1);
        pairBuf[idx] = (uint)s | ((uint)(d & ((1 << BSH) - 1)) << 20);
    }
}

// per-bucket: degrees from LDS hist -> rp + dinv + cursor scatter of col[]
__global__ __launch_bounds__(512)
void bucket_scatter(const uint* __restrict__ pairBuf, const int* __restrict__ bstart,
                    int* __restrict__ col, int* __restrict__ rp,
                    float* __restrict__ dinv, int N) {
    __shared__ int lcnt[1 << BSH];
    __shared__ int lcur[1 << BSH];
    __shared__ int wsum[8];
    int tid = threadIdx.x;
    int lane = tid & 63;
    int w = tid >> 6;
    int b = blockIdx.x;
    int n0 = b << BSH;
    int nn = min(1 << BSH, N - n0);
    int start = bstart[b];
    int end = bstart[b + 1];

    lcnt[tid] = 0;
    __syncthreads();
    for (int e = start + tid; e < end; e += 512)
        atomicAdd(&lcnt[pairBuf[e] >> 20], 1);
    __syncthreads();
    int cnt = lcnt[tid];
    // exclusive scan of 512 degrees (8 waves, shfl scan)
    int x = cnt;
    #pragma unroll
    for (int off = 1; off < 64; off <<= 1) {
        int t = __shfl_up(x, off);
        if (lane >= off) x += t;
    }
    if (lane == 63) wsum[w] = x;
    __syncthreads();
    if (tid == 0) {
        int s = 0;
        #pragma unroll
        for (int k = 0; k < 8; ++k) { int t = wsum[k]; wsum[k] = s; s += t; }
    }
    __syncthreads();
    int excl = start + wsum[w] + (x - cnt);
    if (tid < nn) {
        rp[n0 + tid] = excl;
        dinv[n0 + tid] = rsqrtf((float)cnt + 2.0f);
    }
    lcur[tid] = excl;
    __syncthreads();
    for (int e = start + tid; e < end; e += 512) {
        uint v = pairBuf[e];
        int pos = atomicAdd(&lcur[v >> 20], 1);
        col[pos] = (int)(v & 0xFFFFF);
    }
}

// ---------------- casts / transposes ----------------

__global__ void cast_f32_bf16(const float* __restrict__ src, ushort* __restrict__ dst, int n4) {
    int i = blockIdx.x * blockDim.x + threadIdx.x;
    if (i < n4) {
        float4 v = ((const float4*)src)[i];
        ushort4 o;
        o.x = f2bf(v.x); o.y = f2bf(v.y); o.z = f2bf(v.z); o.w = f2bf(v.w);
        ((ushort4*)dst)[i] = o;
    }
}

// src[K][N] fp32 -> dst[Npad][Kpad] bf16 (zero padded)
__global__ void transpose_cast(const float* __restrict__ src, ushort* __restrict__ dst,
                               int K, int N, int Kpad, int Npad) {
    int idx = blockIdx.x * blockDim.x + threadIdx.x;
    if (idx >= Npad * Kpad) return;
    int n = idx / Kpad, k = idx - n * Kpad;
    float v = (n < N && k < K) ? src[(size_t)k * N + n] : 0.0f;
    dst[idx] = f2bf(v);
}

// ---------------- aggregation (gather over CSR, bf16 rows, fp32 accum) ----------------
// Y[n] = 2*dinv[n]^2 * X[n] + sum_{e in in(n)} dinv[src]*dinv[n] * X[src]
// D=128 split-wave wide-gather kernel (R4 form — best measured). Access-pattern
// restructures (MLP depth R2, load width R4, src-sort R5/R6) all ~null; this
// round probes WORKING-SET CAPACITY: conv2's D=256 aggregation runs as two
// sequential D=128 passes over column halves (25.6MB set each vs 51.2MB),
// since aggregation commutes with column-split.

// D = 128 bf16 (256B rows = 16 uint4): 4 groups of 16 lanes, 4 rows/load
__global__ void aggregate128(const ushort* __restrict__ X, ushort* __restrict__ Y,
                             const int* __restrict__ rp, const int* __restrict__ col,
                             const float* __restrict__ dinv, int N) {
    int gw = blockIdx.x * (blockDim.x >> 6) + (threadIdx.x >> 6);
    int lane = threadIdx.x & 63;
    if (gw >= N) return;
    int g = lane >> 4;        // edge parity class 0..3
    int sub = lane & 15;      // uint4 index within row
    float di = dinv[gw];
    float sc = 2.0f * di * di;
    const uint4* Xr = (const uint4*)X;   // row stride = 16 uint4
    float a[8] = {};
    if (g == 0) acc8(a, Xr[(size_t)gw * 16 + sub], sc);   // self term
    int e = rp[gw], end = rp[gw + 1];
    int base = e;
    for (; base + 8 <= end; base += 8) {
        int c0 = col[base + g];
        int c1 = col[base + 4 + g];
        float w0 = dinv[c0] * di, w1 = dinv[c1] * di;
        uint4 v0 = Xr[(size_t)c0 * 16 + sub];
        uint4 v1 = Xr[(size_t)c1 * 16 + sub];
        acc8(a, v0, w0);
        acc8(a, v1, w1);
    }
    if (base + 4 <= end) {
        int c0 = col[base + g];
        float w0 = dinv[c0] * di;
        acc8(a, Xr[(size_t)c0 * 16 + sub], w0);
        base += 4;
    }
    int rem = end - base;    // 0..3
    if (g < rem) {
        int c0 = col[base + g];
        float w0 = dinv[c0] * di;
        acc8(a, Xr[(size_t)c0 * 16 + sub], w0);
    }
    #pragma unroll
    for (int q = 0; q < 8; ++q) {
        a[q] += __shfl_xor(a[q], 16);
        a[q] += __shfl_xor(a[q], 32);
    }
    if (g == 0) {
        uint4 o;
        o.x = packbf2(a[0], a[1]);
        o.y = packbf2(a[2], a[3]);
        o.z = packbf2(a[4], a[5]);
        o.w = packbf2(a[6], a[7]);
        ((uint4*)Y)[(size_t)gw * 16 + sub] = o;
    }
}

// ---------------- bf16 MFMA GEMMs ----------------
// gemm_wide: 512 threads = 8 waves (2x4), BM=128, BN=256, BK=32, per-wave 64x64.
//   NOTE (R8): occupancy is pinned by acc AGPRs (64/thread, not in VGPR_Count)
//   at ~12 waves/CU for both 4- and 8-wave variants — don't chase occupancy
//   without shrinking the accumulator.
// SPLITA: A stored as two [M,128] half-arrays (A, A2) — conv2 reads the
//   half-split aggregation outputs.
// MODE 0: relu -> bf16 store, SPLIT outputs: cols<128 -> Cout half-array,
//         cols>=128 -> C2 half-array (both [M,128], feeds split aggregation)
// MODE 2: plain -> f32 store
// MODE 3: softplus -> f32 store (Cout) AND tanh(sp*softplus) -> bf16 store (C2,
//         ld 512, cols [Nact,512) zeroed) — feeds the head GEMM.
// NOTE: plain (cached) stores on purpose — R5 showed nontemporal stores break
// L2 write-combining of the 64B epilogue segments (+22% WRITE_SIZE, +50us).

template<int K, int MODE, bool SPLITA>
__global__ __launch_bounds__(512)
void gemm_wide(const ushort* __restrict__ A, const ushort* __restrict__ A2,
               const ushort* __restrict__ BT, const float* __restrict__ bias,
               void* __restrict__ Cout, int M, int Nact, int ldc,
               ushort* __restrict__ C2, const float* __restrict__ thr) {
    __shared__ ushort sA[128 * 32];
    __shared__ ushort sB[256 * 32];
    int tid = threadIdx.x;
    int lane = tid & 63;
    int w = tid >> 6;
    int wr = w >> 2, wc = w & 3;
    int row0 = blockIdx.y * 128;
    int col0 = blockIdx.x * 256;
    float sp = 0.0f;
    if (MODE == 3) sp = softplus_fast(*thr);
    f32x4 acc[4][4] = {};

    for (int kt = 0; kt < K; kt += 32) {
        if (kt) __syncthreads();
        // sA: 8KB = 512 x 16B -> one async copy per thread
        {
            int r = tid >> 2;
            int ko = (tid & 3) * 8;
            int rr = min(row0 + r, M - 1);
            int k = kt + ko;
            const ushort* srcp;
            if (SPLITA)
                srcp = (k < 128) ? (A + (size_t)rr * 128 + k)
                                 : (A2 + (size_t)rr * 128 + (k - 128));
            else
                srcp = A + (size_t)rr * K + k;
            async_copy16(srcp, sA + (size_t)tid * 8);
        }
        // sB: 16KB = 1024 x 16B -> two async copies per thread
        #pragma unroll
        for (int L = 0; L < 2; ++L) {
            int c = L * 512 + tid;
            int nr = c >> 2;
            int ko = (c & 3) * 8;
            async_copy16(BT + (size_t)(col0 + nr) * K + kt + ko, sB + (size_t)c * 8);
        }
        __syncthreads();
        bf16x8 af[4], bfr[4];
        #pragma unroll
        for (int i = 0; i < 4; ++i) {
            int row = wr * 64 + i * 16 + (lane & 15);
            af[i] = *(const bf16x8*)(sA + row * 32 + (lane >> 4) * 8);
        }
        #pragma unroll
        for (int j = 0; j < 4; ++j) {
            int n = wc * 64 + j * 16 + (lane & 15);
            bfr[j] = *(const bf16x8*)(sB + n * 32 + (lane >> 4) * 8);
        }
        #pragma unroll
        for (int i = 0; i < 4; ++i)
            #pragma unroll
            for (int j = 0; j < 4; ++j)
                acc[i][j] = __builtin_amdgcn_mfma_f32_16x16x32_bf16(af[i], bfr[j], acc[i][j], 0, 0, 0);
    }

    #pragma unroll
    for (int i = 0; i < 4; ++i) {
        #pragma unroll
        for (int j = 0; j < 4; ++j) {
            int col = col0 + wc * 64 + j * 16 + (lane & 15);
            if (MODE == 3) {
                bool act = (col < Nact);
                float bv = act ? bias[col] : 0.0f;
                #pragma unroll
                for (int r = 0; r < 4; ++r) {
                    int row = row0 + wr * 64 + i * 16 + (lane >> 4) * 4 + r;
                    if (row >= M) continue;
                    if (act) {
                        float v = softplus_fast(acc[i][j][r] + bv);
                        ((float*)Cout)[(size_t)row * ldc + col] = v;
                        C2[(size_t)row * 512 + col] = f2bf(tanh_fast(sp * v));
                    } else {
                        C2[(size_t)row * 512 + col] = 0;
                    }
                }
            } else if (MODE == 0) {
                if (col >= Nact) continue;
                float bv = bias[col];
                ushort* dsth = (col < 128) ? (ushort*)Cout : C2;
                int ch = col & 127;
                #pragma unroll
                for (int r = 0; r < 4; ++r) {
                    int row = row0 + wr * 64 + i * 16 + (lane >> 4) * 4 + r;
                    if (row >= M) continue;
                    float v = fmaxf(acc[i][j][r] + bv, 0.0f);
                    dsth[(size_t)row * 128 + ch] = f2bf(v);
                }
            } else {
                if (col >= Nact) continue;
                float bv = bias[col];
                #pragma unroll
                for (int r = 0; r < 4; ++r) {
                    int row = row0 + wr * 64 + i * 16 + (lane >> 4) * 4 + r;
                    if (row >= M) continue;
                    ((float*)Cout)[(size_t)row * ldc + col] = acc[i][j][r] + bv;
                }
            }
        }
    }
}

template<int K, int MODE>
__global__ __launch_bounds__(256)
void gemm_bt(const ushort* __restrict__ A, const ushort* __restrict__ BT,
             const float* __restrict__ bias, void* __restrict__ Cout,
             int M, int Nact, int ldc) {
    __shared__ ushort sA[128 * 32];
    __shared__ ushort sB[128 * 32];
    int tid = threadIdx.x;
    int lane = tid & 63;
    int w = tid >> 6;
    int wr = w >> 1, wc = w & 1;
    int row0 = blockIdx.y * 128;
    int col0 = blockIdx.x * 128;
    f32x4 acc[4][4] = {};

    for (int kt = 0; kt < K; kt += 32) {
        if (kt) __syncthreads();
        #pragma unroll
        for (int L = 0; L < 2; ++L) {
            int cb = L * 256 + w * 64;
            int c = cb + lane;
            int r = c >> 2;
            int ko = (c & 3) * 8;
            int rr = min(row0 + r, M - 1);
            async_copy16(A + (size_t)rr * K + kt + ko, sA + (size_t)cb * 8);
        }
        #pragma unroll
        for (int L = 0; L < 2; ++L) {
            int cb = L * 256 + w * 64;
            int c = cb + lane;
            int nr = c >> 2;
            int ko = (c & 3) * 8;
            async_copy16(BT + (size_t)(col0 + nr) * K + kt + ko, sB + (size_t)cb * 8);
        }
        __syncthreads();
        bf16x8 af[4], bfr[4];
        #pragma unroll
        for (int i = 0; i < 4; ++i) {
            int row = wr * 64 + i * 16 + (lane & 15);
            af[i] = *(const bf16x8*)(sA + row * 32 + (lane >> 4) * 8);
        }
        #pragma unroll
        for (int j = 0; j < 4; ++j) {
            int n = wc * 64 + j * 16 + (lane & 15);
            bfr[j] = *(const bf16x8*)(sB + n * 32 + (lane >> 4) * 8);
        }
        #pragma unroll
        for (int i = 0; i < 4; ++i)
            #pragma unroll
            for (int j = 0; j < 4; ++j)
                acc[i][j] = __builtin_amdgcn_mfma_f32_16x16x32_bf16(af[i], bfr[j], acc[i][j], 0, 0, 0);
    }

    #pragma unroll
    for (int i = 0; i < 4; ++i) {
        #pragma unroll
        for (int j = 0; j < 4; ++j) {
            int col = col0 + wc * 64 + j * 16 + (lane & 15);
            if (col >= Nact) continue;
            float bv = bias[col];
            #pragma unroll
            for (int r = 0; r < 4; ++r) {
                int row = row0 + wr * 64 + i * 16 + (lane >> 4) * 4 + r;
                if (row >= M) continue;
                float v = acc[i][j][r] + bv;
                if (MODE == 0) {
                    v = fmaxf(v, 0.0f);
                    ((ushort*)Cout)[(size_t)row * ldc + col] = f2bf(v);
                } else {
                    ((float*)Cout)[(size_t)row * ldc + col] = v;
                }
            }
        }
    }
}

// ---------------- launch ----------------

extern "C" void kernel_launch(void* const* d_in, const int* in_sizes, int n_in,
                              void* d_out, int out_size, void* d_ws, size_t ws_size,
                              hipStream_t stream) {
    const float* x    = (const float*)d_in[0];
    const int*   ei   = (const int*)d_in[1];
    const float* W1   = (const float*)d_in[2];
    const float* b1   = (const float*)d_in[3];
    const float* W2   = (const float*)d_in[4];
    const float* b2   = (const float*)d_in[5];
    const float* Wout = (const float*)d_in[6];
    const float* bout = (const float*)d_in[7];
    const float* thr  = (const float*)d_in[8];

    int N = in_sizes[0] / DIN;
    int E = in_sizes[1] / 2;
    const int* srcI = ei;
    const int* dstI = ei + E;

    char* wsp = (char*)d_ws;
    size_t o = 0;
    auto alloc = [&](size_t bytes) -> void* {
        void* p = wsp + o;
        o = (o + bytes + 255) & ~(size_t)255;
        return p;
    };
    float*  dinv   = (float*)alloc((size_t)N * 4);
    int*    rp     = (int*)alloc((size_t)(N + 1) * 4);
    int*    btot   = (int*)alloc(MAXB * 4);
    int*    bstart = (int*)alloc((MAXB + 1) * 4);
    int*    bcur   = (int*)alloc(MAXB * 4);
    ushort* W1T    = (ushort*)alloc((size_t)256 * 128 * 2);
    ushort* W2T    = (ushort*)alloc((size_t)512 * 256 * 2);
    ushort* WoutT  = (ushort*)alloc((size_t)128 * 512 * 2);
    ushort* bufA   = (ushort*)alloc((size_t)N * 256 * 2);  // xbf+xa, later haA+haB
    // col + hbuf live contiguously; after the aggregate passes both are dead
    // and the region is reused as pbf [N,512] bf16 (tanh activations).
    size_t  col_off = o;
    int*    col   = (int*)alloc((size_t)E * 4);
    ushort* hbuf  = (ushort*)alloc((size_t)N * 256 * 2);  // hA+hB (pairBuf before gemm1)
    size_t  pbf_need = col_off + (size_t)N * 512 * 2;
    if (o < pbf_need) o = (pbf_need + 255) & ~(size_t)255;
    ushort* pbf = (ushort*)(wsp + col_off);               // [N,512] bf16

    ushort* xbf = bufA;                       // [N,128] bf16
    ushort* xa  = bufA + (size_t)N * 128;     // [N,128] bf16
    ushort* haA = bufA;                       // [N,128] bf16 (reuses xbf)
    ushort* haB = bufA + (size_t)N * 128;     // [N,128] bf16 (reuses xa)
    ushort* hA  = hbuf;                       // [N,128] bf16 (cols 0..127 of h)
    ushort* hB  = hbuf + (size_t)N * 128;     // [N,128] bf16 (cols 128..255 of h)
    uint* pairBuf = (uint*)hbuf;              // [E] packed edges (dead before gemm1 writes h)

    float* mr   = (float*)d_out;                    // [N,500]
    float* yout = (float*)d_out + (size_t)N * MODD; // [N,100]

    int mtiles = (N + 127) / 128;
    int NB = (N + (1 << BSH) - 1) >> BSH;           // node-range buckets (196 for N=100K)

    // --- CSR build (fully binned; no per-node random atomics, no global scan) ---
    hipMemsetAsync(btot, 0, (size_t)NB * 4, stream);
    bucket_count<<<(E + PCH - 1) / PCH, 256, 0, stream>>>(dstI, btot, E, NB);
    scan_buckets<<<1, 64, 0, stream>>>(btot, bstart, bcur, rp, NB, N, E);
    partition_edges<<<(E + PCH - 1) / PCH, 256, 0, stream>>>(srcI, dstI, bcur, pairBuf, E, NB);
    bucket_scatter<<<NB, 512, 0, stream>>>(pairBuf, bstart, col, rp, dinv, N);

    // --- weight prep ---
    cast_f32_bf16<<<((N * DIN / 4) + 255) / 256, 256, 0, stream>>>(x, xbf, N * DIN / 4);
    transpose_cast<<<(256 * 128 + 255) / 256, 256, 0, stream>>>(W1, W1T, 128, 256, 128, 256);
    transpose_cast<<<(512 * 256 + 255) / 256, 256, 0, stream>>>(W2, W2T, 256, 500, 256, 512);
    transpose_cast<<<(128 * 512 + 255) / 256, 256, 0, stream>>>(Wout, WoutT, 500, 100, 512, 128);

    // --- conv1 (BN=256 covers all 256 cols; epilogue splits h into hA|hB) ---
    aggregate128<<<(N + 3) / 4, 256, 0, stream>>>(xbf, xa, rp, col, dinv, N);
    gemm_wide<128, 0, false><<<dim3(1, mtiles), 512, 0, stream>>>(
        xa, nullptr, W1T, b1, hA, N, HID, HID, hB, nullptr);

    // --- conv2 aggregation: two sequential D=128 passes (25.6MB set each) ---
    aggregate128<<<(N + 3) / 4, 256, 0, stream>>>(hA, haA, rp, col, dinv, N);
    aggregate128<<<(N + 3) / 4, 256, 0, stream>>>(hB, haB, rp, col, dinv, N);

    // --- conv2 GEMM (split-A; epilogue emits tanh bf16 into pbf) ---
    gemm_wide<256, 3, true><<<dim3(2, mtiles), 512, 0, stream>>>(
        haA, haB, W2T, b2, mr, N, MODD, MODD, pbf, thr);

    // --- head: y = pbf @ Wout + bout ---
    gemm_bt<512, 2><<<dim3(1, mtiles), 256, 0, stream>>>(pbf, WoutT, bout, yout, N, OUTD, OUTD);
}